// Round 15
// baseline (699.500 us; speedup 1.0000x reference)
//
#include <hip/hip_runtime.h>
#include <hip/hip_bf16.h>

// ---------------------------------------------------------------------------
// PDNConv GNN, MI355X round 15.
// Round-14: aggregate x4 (45.7us each) latency-bound (1.7TB/s, VALU 33%,
// occ 69% -> starved for memory-level parallelism); edge_mlp's cost is the
// VALU epilogue, not setup. Changes:
//  - aggregate: 4B uint gathers (2 ch/thread, full 256B row per wave-load),
//    j-space split across the block's 2 waves (serial chain halved), LDS
//    combine of wave partials.
//  - edge_mlp: b1 folded into MFMA via K-pad slot k=16 (A elem = 1.0) —
//    removes 64 v_add per fragment; prep_edge_w writes b1 at k=16.
// Everything else identical to round 14.
// ---------------------------------------------------------------------------

#define NN 50000
#define EE 600000
#define GG 256
#define HID 128
#define EDIM 16
#define EHID 64
#define NL 4
#define MIN_F 200
#define MH 256
#define MOUT 128
#define PH 512
#define PIN 256
#define SCAN_B 196  // ceil(NN/256)
#define PCH 8       // pooling chunks per graph

typedef __hip_bfloat16 bf16;
typedef __attribute__((ext_vector_type(8))) short bf16x8;
typedef __attribute__((ext_vector_type(4))) float f32x4;

__device__ __forceinline__ float bfl(unsigned u) { return __uint_as_float(u << 16); }
__device__ __forceinline__ float bfh(unsigned u) { return __uint_as_float(u & 0xffff0000u); }
__device__ __forceinline__ float b2f(bf16 x) { return __bfloat162float(x); }
__device__ __forceinline__ float ldf(const void* p, long i, bool bf) {
  return bf ? __bfloat162float(((const bf16*)p)[i]) : ((const float*)p)[i];
}
__device__ __forceinline__ unsigned short f2bf_bits(float v) {
  bf16 h = __float2bfloat16(v);
  return *reinterpret_cast<unsigned short*>(&h);
}

// ---------------- dtype probe ------------------------------------------------
__global__ void probe_kernel(const unsigned short* __restrict__ xs, int* flag) {
  if (threadIdx.x == 0 && blockIdx.x == 0) {
    int sane = 0;
    for (int i = 0; i < 128; i++) {
      unsigned e = (xs[i] >> 7) & 0xFF;
      if (e >= 96 && e <= 159) sane++;
    }
    *flag = (sane >= 112) ? 1 : 0;  // 1 = bf16 inputs
  }
}

// ---------------- input -> bf16 conversion (8 elems/thread) -----------------
__global__ __launch_bounds__(256) void cvt_to_bf16(const void* __restrict__ in,
                                                   unsigned short* __restrict__ outp,
                                                   int n8, const int* __restrict__ flag) {
  bool bf = *flag != 0;
  int i = blockIdx.x * 256 + threadIdx.x;
  if (i >= n8) return;
  if (bf) {
    reinterpret_cast<uint4*>(outp)[i] = reinterpret_cast<const uint4*>(in)[i];
  } else {
    const float4* p = reinterpret_cast<const float4*>(in) + (size_t)i * 2;
    float4 v0 = p[0], v1 = p[1];
    ushort4 a, b;
    a.x = f2bf_bits(v0.x); a.y = f2bf_bits(v0.y);
    a.z = f2bf_bits(v0.z); a.w = f2bf_bits(v0.w);
    b.x = f2bf_bits(v1.x); b.y = f2bf_bits(v1.y);
    b.z = f2bf_bits(v1.z); b.w = f2bf_bits(v1.w);
    reinterpret_cast<ushort4*>(outp)[i * 2] = a;
    reinterpret_cast<ushort4*>(outp)[i * 2 + 1] = b;
  }
}

// ---------------- mol_features [G,200] -> padded f32 [G,256] ----------------
__global__ __launch_bounds__(256) void cvt_molf(const void* __restrict__ in,
                                                float* __restrict__ outp,
                                                const int* __restrict__ flag) {
  bool bf = *flag != 0;
  int i = blockIdx.x * 256 + threadIdx.x;  // GG*50
  if (i >= GG * 50) return;
  int row = i / 50, c4 = (i % 50) * 4;
  float4 v;
  if (bf) {
    const unsigned short* p = (const unsigned short*)in + (size_t)row * MIN_F + c4;
    uint2 u = *reinterpret_cast<const uint2*>(p);
    v.x = bfl(u.x); v.y = bfh(u.x); v.z = bfl(u.y); v.w = bfh(u.y);
  } else {
    v = *reinterpret_cast<const float4*>((const float*)in + (size_t)row * MIN_F + c4);
  }
  *reinterpret_cast<float4*>(&outp[(size_t)row * 256 + c4]) = v;
}

// ---------------- weight prep: node GEMM weights -> bf16 Wt[n][k] -----------
__global__ __launch_bounds__(256) void prep_weights(const void* __restrict__ lin_W,
                                                    const void* __restrict__ gW,
                                                    unsigned short* __restrict__ Wt,
                                                    const int* __restrict__ flag) {
  bool bf = *flag != 0;
  int idx = blockIdx.x * 256 + threadIdx.x;  // 0 .. 8*16384-1
  if (idx >= 8 * 16384) return;
  int mat = idx >> 14;
  int rem = idx & 16383;
  int n = rem >> 7, k = rem & 127;
  const void* src = (mat < 4) ? lin_W : gW;
  long srcIdx = (long)(mat & 3) * 16384 + (long)k * 128 + n;
  Wt[idx] = f2bf_bits(ldf(src, srcIdx, bf));
}

// ---------------- weight prep: edge MLP W1 -> bf16 W1t[256 cols][32 K] ------
// k<16: W1; k==16: b1 (MFMA bias-fold: A has 1.0 at k=16); k>16: 0.
__global__ __launch_bounds__(256) void prep_edge_w(const void* __restrict__ mW1,
                                                   const void* __restrict__ mb1,
                                                   unsigned short* __restrict__ W1t,
                                                   const int* __restrict__ flag) {
  bool bf = *flag != 0;
  int idx = blockIdx.x * 256 + threadIdx.x;  // 256*32
  if (idx >= 256 * 32) return;
  int col = idx >> 5, k = idx & 31;
  float v = 0.f;
  if (k < EDIM) v = ldf(mW1, (long)(col >> 6) * (EDIM * EHID) + (long)k * EHID + (col & 63), bf);
  else if (k == EDIM) v = ldf(mb1, col, bf);
  W1t[idx] = f2bf_bits(v);
}

// ---------------- weight prep: tail (MLP+predictor) -> bf16 [N][Kp], K-pad --
__global__ __launch_bounds__(256) void prep_tail(
    const void* __restrict__ mlpW0, const void* __restrict__ mlpW1,
    const void* __restrict__ mlpW2, const void* __restrict__ mlpW3,
    const void* __restrict__ predW0, const void* __restrict__ predW1,
    unsigned short* __restrict__ T, const int* __restrict__ flag) {
  bool bf = *flag != 0;
  int idx = blockIdx.x * 256 + threadIdx.x;
  const void* src; int N, Kp, Ksrc, off;
  if      (idx < 65536)  { src = mlpW0;  N = 256; Kp = 256; Ksrc = 200; off = 0; }
  else if (idx < 131072) { src = mlpW1;  N = 256; Kp = 256; Ksrc = 256; off = 65536; }
  else if (idx < 196608) { src = mlpW2;  N = 256; Kp = 256; Ksrc = 256; off = 131072; }
  else if (idx < 229376) { src = mlpW3;  N = 128; Kp = 256; Ksrc = 256; off = 196608; }
  else if (idx < 360448) { src = predW0; N = 512; Kp = 256; Ksrc = 256; off = 229376; }
  else if (idx < 622592) { src = predW1; N = 512; Kp = 512; Ksrc = 512; off = 360448; }
  else return;
  int rem = idx - off;
  int n = rem / Kp, k = rem % Kp;
  float v = (k < Ksrc) ? ldf(src, (long)k * N + n, bf) : 0.f;
  T[idx] = f2bf_bits(v);
}

// ---------------- CSR build: histogram / 3-phase scan / fill ----------------
__global__ __launch_bounds__(256) void count_kernel(const int* __restrict__ ei,
                                                    int* __restrict__ cnt) {
  int e = blockIdx.x * 256 + threadIdx.x;
  if (e >= EE) return;
  int c = ei[EE + e];
  c = min(max(c, 0), NN - 1);
  atomicAdd(&cnt[c], 1);
}

__global__ __launch_bounds__(256) void scan_phase1(const int* __restrict__ cnt,
                                                   int* __restrict__ bsum) {
  __shared__ int red[256];
  int tid = threadIdx.x;
  int i = blockIdx.x * 256 + tid;
  red[tid] = (i < NN) ? cnt[i] : 0;
  __syncthreads();
  for (int off = 128; off > 0; off >>= 1) {
    if (tid < off) red[tid] += red[tid + off];
    __syncthreads();
  }
  if (tid == 0) bsum[blockIdx.x] = red[0];
}

__global__ __launch_bounds__(256) void scan_phase2(int* __restrict__ bsum,
                                                   int* __restrict__ offs) {
  __shared__ int buf[256];
  int tid = threadIdx.x;
  int v = (tid < SCAN_B) ? bsum[tid] : 0;
  buf[tid] = v;
  __syncthreads();
  for (int off = 1; off < 256; off <<= 1) {
    int t = (tid >= off) ? buf[tid - off] : 0;
    __syncthreads();
    buf[tid] += t;
    __syncthreads();
  }
  if (tid < SCAN_B) bsum[tid] = buf[tid] - v;  // exclusive block offsets
  if (tid == 255) offs[NN] = buf[255];
}

__global__ __launch_bounds__(256) void scan_phase3(const int* __restrict__ cnt,
                                                   const int* __restrict__ bsum,
                                                   int* __restrict__ offs) {
  __shared__ int buf[256];
  int tid = threadIdx.x;
  int i = blockIdx.x * 256 + tid;
  int v = (i < NN) ? cnt[i] : 0;
  buf[tid] = v;
  __syncthreads();
  for (int off = 1; off < 256; off <<= 1) {
    int t = (tid >= off) ? buf[tid - off] : 0;
    __syncthreads();
    buf[tid] += t;
    __syncthreads();
  }
  if (i < NN) offs[i] = bsum[blockIdx.x] + buf[tid] - v;
}

// fill: one int2{src,eid} store per edge
__global__ __launch_bounds__(256) void fill_kernel(const int* __restrict__ ei,
                                                   const int* __restrict__ offs,
                                                   int* __restrict__ cursor,
                                                   int2* __restrict__ csr_se) {
  int e = blockIdx.x * 256 + threadIdx.x;
  if (e >= EE) return;
  int c = ei[EE + e];
  c = min(max(c, 0), NN - 1);
  int pos = offs[c] + atomicAdd(&cursor[c], 1);
  pos = min(max(pos, 0), EE - 1);
  csr_se[pos] = make_int2(ei[e], e);
}

// ---------------- edge-gate MLP via MFMA: ORIGINAL edge order ---------------
// b1 folded into MFMA (k=16 slot, A elem = 1.0). 8 fragments per wave.
__global__ __launch_bounds__(256) void edge_mlp_mfma(
    const void* __restrict__ eattr, const unsigned short* __restrict__ W1t,
    const void* __restrict__ mW2, const void* __restrict__ mb2,
    float* __restrict__ w_all4, const int* __restrict__ flag) {
  bool bf = *flag != 0;
  int tid = threadIdx.x;
  int wave = tid >> 6, lane = tid & 63;
  int l15 = lane & 15, quad = lane >> 4;

  bf16x8 bfrag[16];
#pragma unroll
  for (int t = 0; t < 16; t++)
    bfrag[t] = *reinterpret_cast<const bf16x8*>(&W1t[(t * 16 + l15) * 32 + quad * 8]);

  float w2v[16];
#pragma unroll
  for (int t = 0; t < 16; t++) w2v[t] = ldf(mW2, t * 16 + l15, bf);
  float b2v0 = ldf(mb2, 0, bf), b2v1 = ldf(mb2, 1, bf);
  float b2v2 = ldf(mb2, 2, bf), b2v3 = ldf(mb2, 3, bf);
  float b2 = b2v0;
  b2 = (l15 == 1) ? b2v1 : b2;
  b2 = (l15 == 2) ? b2v2 : b2;
  b2 = (l15 == 3) ? b2v3 : b2;
  bool o1 = (l15 & 1) != 0;
  bool o2 = (l15 & 2) != 0;

  int ebase = blockIdx.x * 512 + wave * 128;
#pragma unroll 1
  for (int f = 0; f < 8; f++) {
    int fbase = ebase + f * 16;
    if (fbase < EE) {  // EE%16==0 -> whole fragment in-bounds
      long erow = fbase + l15;
      bf16x8 a = (bf16x8){0, 0, 0, 0, 0, 0, 0, 0};
      if (quad < 2) {
        if (bf) {
          uint4 v = *reinterpret_cast<const uint4*>((const bf16*)eattr + erow * EDIM + quad * 8);
          a = *reinterpret_cast<bf16x8*>(&v);
        } else {
          const float4* p =
              reinterpret_cast<const float4*>((const float*)eattr + erow * EDIM + quad * 8);
          float4 v0 = p[0], v1 = p[1];
          a[0] = (short)f2bf_bits(v0.x); a[1] = (short)f2bf_bits(v0.y);
          a[2] = (short)f2bf_bits(v0.z); a[3] = (short)f2bf_bits(v0.w);
          a[4] = (short)f2bf_bits(v1.x); a[5] = (short)f2bf_bits(v1.y);
          a[6] = (short)f2bf_bits(v1.z); a[7] = (short)f2bf_bits(v1.w);
        }
      }
      if (quad == 2) a[0] = (short)0x3F80;  // k=16 element = bf16(1.0): adds b1
      float s00 = 0.f, s01 = 0.f, s02 = 0.f, s03 = 0.f;
      float s10 = 0.f, s11 = 0.f, s12 = 0.f, s13 = 0.f;
      float s20 = 0.f, s21 = 0.f, s22 = 0.f, s23 = 0.f;
      float s30 = 0.f, s31 = 0.f, s32 = 0.f, s33 = 0.f;
#define DO_T(T, S0, S1, S2, S3)                                               \
  {                                                                           \
    f32x4 acc = __builtin_amdgcn_mfma_f32_16x16x32_bf16(                      \
        a, bfrag[T], (f32x4){0.f, 0.f, 0.f, 0.f}, 0, 0, 0);                   \
    S0 += fmaxf(acc.x, 0.f) * w2v[T];                                         \
    S1 += fmaxf(acc.y, 0.f) * w2v[T];                                         \
    S2 += fmaxf(acc.z, 0.f) * w2v[T];                                         \
    S3 += fmaxf(acc.w, 0.f) * w2v[T];                                         \
  }
      DO_T(0,  s00, s01, s02, s03) DO_T(1,  s00, s01, s02, s03)
      DO_T(2,  s00, s01, s02, s03) DO_T(3,  s00, s01, s02, s03)
      DO_T(4,  s10, s11, s12, s13) DO_T(5,  s10, s11, s12, s13)
      DO_T(6,  s10, s11, s12, s13) DO_T(7,  s10, s11, s12, s13)
      DO_T(8,  s20, s21, s22, s23) DO_T(9,  s20, s21, s22, s23)
      DO_T(10, s20, s21, s22, s23) DO_T(11, s20, s21, s22, s23)
      DO_T(12, s30, s31, s32, s33) DO_T(13, s30, s31, s32, s33)
      DO_T(14, s30, s31, s32, s33) DO_T(15, s30, s31, s32, s33)
#undef DO_T
#define RS_STEP1(AR, S0R, S1R) \
  float AR = (o1 ? S1R : S0R) + __shfl_xor(o1 ? S0R : S1R, 1);
      RS_STEP1(a0, s00, s10)
      RS_STEP1(a1, s01, s11)
      RS_STEP1(a2, s02, s12)
      RS_STEP1(a3, s03, s13)
      RS_STEP1(bb0, s20, s30)
      RS_STEP1(bb1, s21, s31)
      RS_STEP1(bb2, s22, s32)
      RS_STEP1(bb3, s23, s33)
#undef RS_STEP1
      float c0 = (o2 ? bb0 : a0) + __shfl_xor(o2 ? a0 : bb0, 2);
      float c1 = (o2 ? bb1 : a1) + __shfl_xor(o2 ? a1 : bb1, 2);
      float c2 = (o2 ? bb2 : a2) + __shfl_xor(o2 ? a2 : bb2, 2);
      float c3 = (o2 ? bb3 : a3) + __shfl_xor(o2 ? a3 : bb3, 2);
      c0 += __shfl_xor(c0, 4); c1 += __shfl_xor(c1, 4);
      c2 += __shfl_xor(c2, 4); c3 += __shfl_xor(c3, 4);
      c0 += __shfl_xor(c0, 8); c1 += __shfl_xor(c1, 8);
      c2 += __shfl_xor(c2, 8); c3 += __shfl_xor(c3, 8);
      if (l15 < NL) {
        float g0 = 1.f / (1.f + __expf(-(c0 + b2)));
        float g1 = 1.f / (1.f + __expf(-(c1 + b2)));
        float g2 = 1.f / (1.f + __expf(-(c2 + b2)));
        float g3 = 1.f / (1.f + __expf(-(c3 + b2)));
        w_all4[(size_t)(fbase + quad * 4 + 0) * 4 + l15] = g0;
        w_all4[(size_t)(fbase + quad * 4 + 1) * 4 + l15] = g1;
        w_all4[(size_t)(fbase + quad * 4 + 2) * 4 + l15] = g2;
        w_all4[(size_t)(fbase + quad * 4 + 3) * 4 + l15] = g3;
      }
    }
  }
}

// ---------------- gather gates into CSR order -------------------------------
__global__ __launch_bounds__(256) void csr_gather(const int2* __restrict__ csr_se,
                                                  const float* __restrict__ w_all4,
                                                  float* __restrict__ csr_val) {
  int k = blockIdx.x * 256 + threadIdx.x;
  if (k >= EE) return;
  int eid = csr_se[k].y;
  eid = min(max(eid, 0), EE - 1);
  float4 w = reinterpret_cast<const float4*>(w_all4)[eid];
  csr_val[k] = w.x;
  csr_val[(size_t)EE + k] = w.y;
  csr_val[2 * (size_t)EE + k] = w.z;
  csr_val[3 * (size_t)EE + k] = w.w;
}

// ---------------- degree / dinv per layer (interleaved float4 out) ----------
__global__ __launch_bounds__(256) void deg_kernel(const int* __restrict__ offs,
                                                  const float* __restrict__ csr_val,
                                                  float* __restrict__ dinv4) {
  int n = blockIdx.x * 256 + threadIdx.x;
  if (n >= NN) return;
  int s = offs[n], e = offs[n + 1];
  float d0 = 1.f, d1 = 1.f, d2 = 1.f, d3 = 1.f;  // self-loop weight 1.0
  for (int k = s; k < e; k++) {
    d0 += csr_val[k];
    d1 += csr_val[EE + k];
    d2 += csr_val[2 * (size_t)EE + k];
    d3 += csr_val[3 * (size_t)EE + k];
  }
  float4 o;
  o.x = rsqrtf(d0); o.y = rsqrtf(d1); o.z = rsqrtf(d2); o.w = rsqrtf(d3);
  reinterpret_cast<float4*>(dinv4)[n] = o;
}

// csr_val[l][k] *= dinv_l[src_k]
__global__ __launch_bounds__(256) void csr_scale_kernel(const int2* __restrict__ csr_se,
                                                        const float* __restrict__ dinv4,
                                                        float* __restrict__ csr_val) {
  int k = blockIdx.x * 256 + threadIdx.x;
  if (k >= EE) return;
  int s = csr_se[k].x;
  s = min(max(s, 0), NN - 1);
  float4 d = reinterpret_cast<const float4*>(dinv4)[s];
  csr_val[k] *= d.x;
  csr_val[(size_t)EE + k] *= d.y;
  csr_val[2 * (size_t)EE + k] *= d.z;
  csr_val[3 * (size_t)EE + k] *= d.w;
}

// ---------------- node GEMM via MFMA: bf16 in, bf16 out ---------------------
__global__ __launch_bounds__(256) void gemm_nodes_bf16(
    const unsigned short* __restrict__ A16, const unsigned short* __restrict__ Wt,
    const void* __restrict__ bias, long boff, unsigned short* __restrict__ out16,
    int relu, const int* __restrict__ flag) {
  __shared__ alignas(16) unsigned short sA[64 * 136];
  __shared__ alignas(16) unsigned short sW[128 * 136];
  int tid = threadIdx.x;
  int rbase = blockIdx.x * 64;

#pragma unroll
  for (int p = 0; p < 8; p++) {
    int idx8 = p * 256 + tid;
    int n = idx8 >> 4, kc = idx8 & 15;
    uint4 v = reinterpret_cast<const uint4*>(Wt)[idx8];
    *reinterpret_cast<uint4*>(&sW[n * 136 + kc * 8]) = v;
  }
#pragma unroll
  for (int p = 0; p < 4; p++) {
    int idx8 = p * 256 + tid;
    int m = idx8 >> 4, kc = idx8 & 15;
    int row = rbase + m;
    uint4 v = make_uint4(0u, 0u, 0u, 0u);
    if (row < NN)
      v = *reinterpret_cast<const uint4*>(&A16[(size_t)row * HID + kc * 8]);
    *reinterpret_cast<uint4*>(&sA[m * 136 + kc * 8]) = v;
  }
  __syncthreads();

  int wave = tid >> 6, lane = tid & 63;
  int l15 = lane & 15, quad = lane >> 4;
  int mstrip = wave * 16;

  f32x4 acc[8];
#pragma unroll
  for (int t = 0; t < 8; t++) acc[t] = (f32x4){0.f, 0.f, 0.f, 0.f};

#pragma unroll
  for (int ks = 0; ks < 4; ks++) {
    int k0 = ks * 32 + quad * 8;
    bf16x8 a = *reinterpret_cast<const bf16x8*>(&sA[(mstrip + l15) * 136 + k0]);
#pragma unroll
    for (int t = 0; t < 8; t++) {
      bf16x8 b = *reinterpret_cast<const bf16x8*>(&sW[(t * 16 + l15) * 136 + k0]);
      acc[t] = __builtin_amdgcn_mfma_f32_16x16x32_bf16(a, b, acc[t], 0, 0, 0);
    }
  }

  bool bf = *flag != 0;
#pragma unroll
  for (int t = 0; t < 8; t++) {
    int n = t * 16 + l15;
    float bv = (boff >= 0) ? ldf(bias, boff + n, bf) : 0.f;
#pragma unroll
    for (int r = 0; r < 4; r++) {
      int row = rbase + mstrip + quad * 4 + r;
      if (row < NN) {
        float o = acc[t][r] + bv;
        if (relu) o = fmaxf(o, 0.f);
        out16[(size_t)row * HID + n] = f2bf_bits(o);
      }
    }
  }
}

// ---------------- tail GEMM via MFMA ----------------------------------------
__global__ __launch_bounds__(256) void gemm_tail_mfma(
    const float* __restrict__ A, int lda, const unsigned short* __restrict__ Wt,
    int Kp, const void* __restrict__ bias, float* __restrict__ outp, int ldo,
    int relu, const int* __restrict__ flag) {
  __shared__ alignas(16) unsigned short sA[64 * 264];
  __shared__ alignas(16) unsigned short sW[64 * 264];
  int tid = threadIdx.x;
  int rbase = blockIdx.x * 64;
  int nbase = blockIdx.y * 64;
  int wave = tid >> 6, lane = tid & 63;
  int l15 = lane & 15, quad = lane >> 4;
  int mstrip = wave * 16;

  f32x4 acc[4];
#pragma unroll
  for (int t = 0; t < 4; t++) acc[t] = (f32x4){0.f, 0.f, 0.f, 0.f};

  for (int kc = 0; kc < Kp; kc += 256) {
#pragma unroll 4
    for (int p = 0; p < 16; p++) {
      int idx = p * 1024 + tid * 4;
      int m = idx >> 8, k = idx & 255;
      float4 v = *reinterpret_cast<const float4*>(&A[(size_t)(rbase + m) * lda + kc + k]);
      ushort4 b;
      b.x = f2bf_bits(v.x); b.y = f2bf_bits(v.y);
      b.z = f2bf_bits(v.z); b.w = f2bf_bits(v.w);
      *reinterpret_cast<ushort4*>(&sA[m * 264 + k]) = b;
    }
#pragma unroll 4
    for (int p = 0; p < 8; p++) {
      int idx8 = p * 256 + tid;
      int n = idx8 >> 5, kk = (idx8 & 31) * 8;
      uint4 v = *reinterpret_cast<const uint4*>(&Wt[(size_t)(nbase + n) * Kp + kc + kk]);
      *reinterpret_cast<uint4*>(&sW[n * 264 + kk]) = v;
    }
    __syncthreads();
#pragma unroll
    for (int ks = 0; ks < 8; ks++) {
      int k0 = ks * 32 + quad * 8;
      bf16x8 a = *reinterpret_cast<const bf16x8*>(&sA[(mstrip + l15) * 264 + k0]);
#pragma unroll
      for (int nt = 0; nt < 4; nt++) {
        bf16x8 b = *reinterpret_cast<const bf16x8*>(&sW[(nt * 16 + l15) * 264 + k0]);
        acc[nt] = __builtin_amdgcn_mfma_f32_16x16x32_bf16(a, b, acc[nt], 0, 0, 0);
      }
    }
    __syncthreads();
  }

  bool bf = *flag != 0;
#pragma unroll
  for (int nt = 0; nt < 4; nt++) {
    int col = nbase + nt * 16 + l15;
    float bv = ldf(bias, col, bf);
#pragma unroll
    for (int r = 0; r < 4; r++) {
      int row = rbase + mstrip + quad * 4 + r;
      float o = acc[nt][r] + bv;
      if (relu) o = fmaxf(o, 0.f);
      outp[(size_t)row * ldo + col] = o;
    }
  }
}

// ---------------- aggregation: uint gathers, 2-wave j-split -----------------
// thread = (c2 = channel pair, jw = wave). Each wave's gather covers the
// full 256B row; j-space split across the 2 waves; LDS combine.
__global__ __launch_bounds__(128) void aggregate_kernel(
    const unsigned short* __restrict__ hl16, const int* __restrict__ offs,
    const int2* __restrict__ csr_se, const float* __restrict__ csr_val,
    const float* __restrict__ dinv4, int layer, const void* __restrict__ bias,
    long boff, unsigned short* __restrict__ out16, const int* __restrict__ flag) {
  bool bf = *flag != 0;
  int n = blockIdx.x;
  int tid = threadIdx.x;
  int c2 = tid & 63, jw = tid >> 6;
  __shared__ int s_src[128];
  __shared__ float s_val[128];
  __shared__ float2 s_part[64];
  int start = offs[n], end = offs[n + 1];
  float a0 = 0.f, a1 = 0.f;
  for (int base = start; base < end; base += 128) {
    int k = base + tid;
    if (k < end) {
      s_src[tid] = min(max(csr_se[k].x, 0), NN - 1);
      s_val[tid] = csr_val[k];
    }
    __syncthreads();
    int m = min(128, end - base);
    for (int j = jw; j < m; j += 2) {
      float v = s_val[j];
      unsigned u = *reinterpret_cast<const unsigned*>(
          &hl16[(size_t)s_src[j] * HID + 2 * c2]);
      a0 = fmaf(v, bfl(u), a0);
      a1 = fmaf(v, bfh(u), a1);
    }
    __syncthreads();
  }
  if (jw == 1) s_part[c2] = make_float2(a0, a1);
  __syncthreads();
  if (jw == 0) {
    float2 p = s_part[c2];
    a0 += p.x; a1 += p.y;
    float dn = dinv4[(size_t)n * 4 + layer];
    unsigned su = *reinterpret_cast<const unsigned*>(&hl16[(size_t)n * HID + 2 * c2]);
    float bv0 = ldf(bias, boff + 2 * c2, bf);
    float bv1 = ldf(bias, boff + 2 * c2 + 1, bf);
    ushort2 o;
    o.x = f2bf_bits(dn * a0 + dn * dn * bfl(su) + bv0);
    o.y = f2bf_bits(dn * a1 + dn * dn * bfh(su) + bv1);
    *reinterpret_cast<ushort2*>(&out16[(size_t)n * HID + 2 * c2]) = o;
  }
}

// ---------------- mean pool, 2-phase (bf16 input) ---------------------------
__global__ __launch_bounds__(128) void pool_partial(const unsigned short* __restrict__ h16,
                                                    const int* __restrict__ batch,
                                                    float* __restrict__ part) {
  int g = blockIdx.x, chunk = blockIdx.y, c = threadIdx.x;
  int lo = 0, hi = NN;
  while (lo < hi) { int mid = (lo + hi) >> 1; if (batch[mid] < g) lo = mid + 1; else hi = mid; }
  int start = lo;
  hi = NN;
  while (lo < hi) { int mid = (lo + hi) >> 1; if (batch[mid] < g + 1) lo = mid + 1; else hi = mid; }
  int end = lo;
  int len = end - start;
  int per = (len + PCH - 1) / PCH;
  int s = start + chunk * per;
  int e = min(s + per, end);
  float sum = 0.f;
  for (int n = s; n < e; n++) sum += bfl((unsigned)h16[(size_t)n * HID + c]);
  part[((size_t)g * PCH + chunk) * HID + c] = sum;
}

__global__ __launch_bounds__(128) void pool_combine(const float* __restrict__ part,
                                                    const int* __restrict__ batch,
                                                    float* __restrict__ cat) {
  int g = blockIdx.x, c = threadIdx.x;
  int lo = 0, hi = NN;
  while (lo < hi) { int mid = (lo + hi) >> 1; if (batch[mid] < g) lo = mid + 1; else hi = mid; }
  int start = lo;
  hi = NN;
  while (lo < hi) { int mid = (lo + hi) >> 1; if (batch[mid] < g + 1) lo = mid + 1; else hi = mid; }
  int end = lo;
  float s = 0.f;
#pragma unroll
  for (int k = 0; k < PCH; k++) s += part[((size_t)g * PCH + k) * HID + c];
  float cntf = (float)(end - start);
  cat[(size_t)g * PIN + c] = s / fmaxf(cntf, 1.f);
}

// ---------------- final [G,512] @ [512,1] + b -> out ------------------------
__global__ __launch_bounds__(64) void final_kernel(const float* __restrict__ A,
                                                   const void* __restrict__ W,
                                                   const void* __restrict__ b,
                                                   void* __restrict__ outp,
                                                   const int* __restrict__ flag) {
  bool bf = *flag != 0;
  int g = blockIdx.x, lane = threadIdx.x;
  float s = 0.f;
  for (int k = lane; k < PH; k += 64) s = fmaf(A[(size_t)g * PH + k], ldf(W, k, bf), s);
#pragma unroll
  for (int off = 32; off > 0; off >>= 1) s += __shfl_down(s, off);
  if (lane == 0) {
    float r = s + ldf(b, 0, bf);
    if (bf) ((bf16*)outp)[g] = __float2bfloat16(r);
    else    ((float*)outp)[g] = r;
  }
}

// ---------------------------------------------------------------------------
extern "C" void kernel_launch(void* const* d_in, const int* in_sizes, int n_in,
                              void* d_out, int out_size, void* d_ws, size_t ws_size,
                              hipStream_t stream) {
  const void* x      = d_in[0];
  const int*  ei     = (const int*)d_in[1];
  const void* eattr  = d_in[2];
  const int*  batch  = (const int*)d_in[3];
  const void* molf   = d_in[4];
  const void* lin_W  = d_in[5];
  const void* mW1    = d_in[6];
  const void* mb1    = d_in[7];
  const void* mW2    = d_in[8];
  const void* mb2    = d_in[9];
  const void* cbias  = d_in[10];
  const void* gW     = d_in[11];
  const void* gb     = d_in[12];
  const void* mlpW0  = d_in[13];
  const void* mlpb0  = d_in[14];
  const void* mlpW1  = d_in[15];
  const void* mlpb1  = d_in[16];
  const void* mlpW2  = d_in[17];
  const void* mlpb2  = d_in[18];
  const void* mlpW3  = d_in[19];
  const void* mlpb3  = d_in[20];
  const void* predW0 = d_in[21];
  const void* predb0 = d_in[22];
  const void* predW1 = d_in[23];
  const void* predb1 = d_in[24];
  const void* outW   = d_in[25];
  const void* outb   = d_in[26];

  char* base = (char*)d_ws;
  size_t off = 0;
  auto alloc = [&](size_t bytes) -> char* {
    char* p = base + off;
    off = (off + bytes + 255) & ~(size_t)255;
    return p;
  };
  unsigned short* h16  = (unsigned short*)alloc((size_t)NN * HID * 2);
  unsigned short* t16  = (unsigned short*)alloc((size_t)NN * HID * 2);
  unsigned short* hl16 = (unsigned short*)alloc((size_t)NN * HID * 2);
  float* dinv4    = (float*)alloc((size_t)NN * 4 * 4);
  int*   cnt      = (int*)alloc((size_t)NN * 4);
  int*   offs     = (int*)alloc((size_t)(NN + 1) * 4);
  int*   cursor   = (int*)alloc((size_t)NN * 4);
  int*   bsum     = (int*)alloc((size_t)256 * 4);
  int2*  csr_se   = (int2*)alloc((size_t)EE * 8);
  float* csr_val  = (float*)alloc((size_t)NL * EE * 4);
  float* w_all4   = (float*)alloc((size_t)EE * 4 * 4);
  unsigned short* Wt    = (unsigned short*)alloc((size_t)8 * HID * HID * 2);
  unsigned short* tailW = (unsigned short*)alloc((size_t)622592 * 2);
  unsigned short* edgeW = (unsigned short*)alloc((size_t)256 * 32 * 2);
  int*   flag     = (int*)alloc(256);
  float* part     = (float*)alloc((size_t)GG * PCH * HID * 4);
  float* molf32   = (float*)alloc((size_t)GG * 256 * 4);
  float* m0       = (float*)alloc((size_t)GG * MH * 4);
  float* m1       = (float*)alloc((size_t)GG * MH * 4);
  float* cat      = (float*)alloc((size_t)GG * PIN * 4);
  float* p0       = (float*)alloc((size_t)GG * PH * 4);
  float* p1       = (float*)alloc((size_t)GG * PH * 4);

  hipMemsetAsync(cnt, 0, (size_t)NN * 4, stream);
  hipMemsetAsync(cursor, 0, (size_t)NN * 4, stream);
  hipMemsetAsync(molf32, 0, (size_t)GG * 256 * 4, stream);

  // dtype probe first — everything downstream branches on it
  probe_kernel<<<1, 64, 0, stream>>>((const unsigned short*)x, flag);

  // weight prep
  prep_weights<<<512, 256, 0, stream>>>(lin_W, gW, Wt, flag);
  prep_tail<<<(622592 + 255) / 256, 256, 0, stream>>>(mlpW0, mlpW1, mlpW2, mlpW3,
                                                      predW0, predW1, tailW, flag);
  prep_edge_w<<<32, 256, 0, stream>>>(mW1, mb1, edgeW, flag);

  // x -> bf16 layer state
  {
    int n8 = NN * HID / 8;
    cvt_to_bf16<<<(n8 + 255) / 256, 256, 0, stream>>>(x, h16, n8, flag);
  }
  // edge gates (MFMA, ORIGINAL order, 8 frags/wave, b1 folded into MFMA)
  edge_mlp_mfma<<<(EE + 511) / 512, 256, 0, stream>>>(eattr, edgeW, mW2, mb2,
                                                      w_all4, flag);
  // CSR build (3-phase parallel scan)
  count_kernel<<<(EE + 255) / 256, 256, 0, stream>>>(ei, cnt);
  scan_phase1<<<SCAN_B, 256, 0, stream>>>(cnt, bsum);
  scan_phase2<<<1, 256, 0, stream>>>(bsum, offs);
  scan_phase3<<<SCAN_B, 256, 0, stream>>>(cnt, bsum, offs);
  fill_kernel<<<(EE + 255) / 256, 256, 0, stream>>>(ei, offs, cursor, csr_se);
  // permute gates to CSR order, degrees, scaling
  csr_gather<<<(EE + 255) / 256, 256, 0, stream>>>(csr_se, w_all4, csr_val);
  deg_kernel<<<(NN + 255) / 256, 256, 0, stream>>>(offs, csr_val, dinv4);
  csr_scale_kernel<<<(EE + 255) / 256, 256, 0, stream>>>(csr_se, dinv4, csr_val);

  // GCN layers: lin(h16)->hl16; aggregate(hl16)->t16; gcn(t16)->h16
  const int gemm_blocks = (NN + 63) / 64;  // 782
  for (int l = 0; l < NL; l++) {
    gemm_nodes_bf16<<<gemm_blocks, 256, 0, stream>>>(
        h16, Wt + (size_t)l * HID * HID, nullptr, -1, hl16, 0, flag);
    aggregate_kernel<<<NN, 128, 0, stream>>>(hl16, offs, csr_se,
                                             csr_val + (size_t)l * EE, dinv4, l,
                                             cbias, (long)l * HID, t16, flag);
    gemm_nodes_bf16<<<gemm_blocks, 256, 0, stream>>>(
        t16, Wt + (size_t)(4 + l) * HID * HID, gb, (long)l * HID, h16, 1, flag);
  }

  // pooling -> cat[:, 0:128]  (2-phase, bf16 input)
  pool_partial<<<dim3(GG, PCH), 128, 0, stream>>>(h16, batch, part);
  pool_combine<<<GG, 128, 0, stream>>>(part, batch, cat);

  // molecular MLP -> cat[:, 128:256]  (MFMA tail, K-padded weights)
  cvt_molf<<<(GG * 50 + 255) / 256, 256, 0, stream>>>(molf, molf32, flag);
  gemm_tail_mfma<<<dim3(4, 4), 256, 0, stream>>>(molf32, 256, tailW + 0,      256, mlpb0, m0, 256, 1, flag);
  gemm_tail_mfma<<<dim3(4, 4), 256, 0, stream>>>(m0,     256, tailW + 65536,  256, mlpb1, m1, 256, 1, flag);
  gemm_tail_mfma<<<dim3(4, 4), 256, 0, stream>>>(m1,     256, tailW + 131072, 256, mlpb2, m0, 256, 1, flag);
  gemm_tail_mfma<<<dim3(4, 2), 256, 0, stream>>>(m0,     256, tailW + 196608, 256, mlpb3, cat + MOUT, 256, 1, flag);

  // predictor
  gemm_tail_mfma<<<dim3(4, 8), 256, 0, stream>>>(cat, 256, tailW + 229376, 256, predb0, p0, 512, 1, flag);
  gemm_tail_mfma<<<dim3(4, 8), 256, 0, stream>>>(p0,  512, tailW + 360448, 512, predb1, p1, 512, 1, flag);
  final_kernel<<<GG, 64, 0, stream>>>(p1, outW, outb, d_out, flag);
}

// Round 16
// 640.649 us; speedup vs baseline: 1.0919x; 1.0919x over previous
//
#include <hip/hip_runtime.h>
#include <hip/hip_bf16.h>

// ---------------------------------------------------------------------------
// PDNConv GNN, MI355X round 16.
// Round-15 post-mortem: aggregate j-split regressed (45.7->50.7us) — reverted
// to the round-14 aggregate. Kept the edge b1-MFMA fold.
// NEW: aggregation commutes with the linear map —
//   relu((Agg(h)@linW + cbias)@gW + gb) = relu(Agg(h)@(linW·gW) + (cbias·gW+gb))
// so W'_l = linW_l·gW_l (bf16,[n][k]) and b'_l (f32) are precomputed once and
// the layer loop is: aggregate(h16)->t16; gemm(t16,W',b',relu)->h16.
// 4 node GEMMs instead of 8; hl16 buffer and its traffic eliminated.
// ---------------------------------------------------------------------------

#define NN 50000
#define EE 600000
#define GG 256
#define HID 128
#define EDIM 16
#define EHID 64
#define NL 4
#define MIN_F 200
#define MH 256
#define MOUT 128
#define PH 512
#define PIN 256
#define SCAN_B 196  // ceil(NN/256)
#define PCH 8       // pooling chunks per graph

typedef __hip_bfloat16 bf16;
typedef __attribute__((ext_vector_type(8))) short bf16x8;
typedef __attribute__((ext_vector_type(4))) float f32x4;

__device__ __forceinline__ float bfl(unsigned u) { return __uint_as_float(u << 16); }
__device__ __forceinline__ float bfh(unsigned u) { return __uint_as_float(u & 0xffff0000u); }
__device__ __forceinline__ float b2f(bf16 x) { return __bfloat162float(x); }
__device__ __forceinline__ float ldf(const void* p, long i, bool bf) {
  return bf ? __bfloat162float(((const bf16*)p)[i]) : ((const float*)p)[i];
}
__device__ __forceinline__ unsigned short f2bf_bits(float v) {
  bf16 h = __float2bfloat16(v);
  return *reinterpret_cast<unsigned short*>(&h);
}

// ---------------- dtype probe ------------------------------------------------
__global__ void probe_kernel(const unsigned short* __restrict__ xs, int* flag) {
  if (threadIdx.x == 0 && blockIdx.x == 0) {
    int sane = 0;
    for (int i = 0; i < 128; i++) {
      unsigned e = (xs[i] >> 7) & 0xFF;
      if (e >= 96 && e <= 159) sane++;
    }
    *flag = (sane >= 112) ? 1 : 0;  // 1 = bf16 inputs
  }
}

// ---------------- input -> bf16 conversion (8 elems/thread) -----------------
__global__ __launch_bounds__(256) void cvt_to_bf16(const void* __restrict__ in,
                                                   unsigned short* __restrict__ outp,
                                                   int n8, const int* __restrict__ flag) {
  bool bf = *flag != 0;
  int i = blockIdx.x * 256 + threadIdx.x;
  if (i >= n8) return;
  if (bf) {
    reinterpret_cast<uint4*>(outp)[i] = reinterpret_cast<const uint4*>(in)[i];
  } else {
    const float4* p = reinterpret_cast<const float4*>(in) + (size_t)i * 2;
    float4 v0 = p[0], v1 = p[1];
    ushort4 a, b;
    a.x = f2bf_bits(v0.x); a.y = f2bf_bits(v0.y);
    a.z = f2bf_bits(v0.z); a.w = f2bf_bits(v0.w);
    b.x = f2bf_bits(v1.x); b.y = f2bf_bits(v1.y);
    b.z = f2bf_bits(v1.z); b.w = f2bf_bits(v1.w);
    reinterpret_cast<ushort4*>(outp)[i * 2] = a;
    reinterpret_cast<ushort4*>(outp)[i * 2 + 1] = b;
  }
}

// ---------------- mol_features [G,200] -> padded f32 [G,256] ----------------
__global__ __launch_bounds__(256) void cvt_molf(const void* __restrict__ in,
                                                float* __restrict__ outp,
                                                const int* __restrict__ flag) {
  bool bf = *flag != 0;
  int i = blockIdx.x * 256 + threadIdx.x;  // GG*50
  if (i >= GG * 50) return;
  int row = i / 50, c4 = (i % 50) * 4;
  float4 v;
  if (bf) {
    const unsigned short* p = (const unsigned short*)in + (size_t)row * MIN_F + c4;
    uint2 u = *reinterpret_cast<const uint2*>(p);
    v.x = bfl(u.x); v.y = bfh(u.x); v.z = bfl(u.y); v.w = bfh(u.y);
  } else {
    v = *reinterpret_cast<const float4*>((const float*)in + (size_t)row * MIN_F + c4);
  }
  *reinterpret_cast<float4*>(&outp[(size_t)row * 256 + c4]) = v;
}

// ---------------- weight prep: fused W'_l = linW_l @ gW_l -> bf16 [n][k] ----
__global__ __launch_bounds__(256) void prep_fused_w(const void* __restrict__ lin_W,
                                                    const void* __restrict__ gW,
                                                    unsigned short* __restrict__ Wt,
                                                    const int* __restrict__ flag) {
  bool bf = *flag != 0;
  int idx = blockIdx.x * 256 + threadIdx.x;  // 0 .. 4*16384-1
  if (idx >= 4 * 16384) return;
  int l = idx >> 14;
  int rem = idx & 16383;
  int n = rem >> 7, k = rem & 127;  // Wt[n][k] = W'[k][n]
  float s = 0.f;
  long lb = (long)l * 16384;
  for (int m = 0; m < 128; m++)
    s += ldf(lin_W, lb + (long)k * 128 + m, bf) * ldf(gW, lb + (long)m * 128 + n, bf);
  Wt[idx] = f2bf_bits(s);
}

// b'_l[n] = gb_l[n] + sum_k cbias_l[k] * gW_l[k][n]   (f32)
__global__ __launch_bounds__(128) void prep_fused_b(const void* __restrict__ cbias,
                                                    const void* __restrict__ gW,
                                                    const void* __restrict__ gb,
                                                    float* __restrict__ bprime,
                                                    const int* __restrict__ flag) {
  bool bf = *flag != 0;
  int idx = blockIdx.x * 128 + threadIdx.x;  // 0 .. 4*128-1
  if (idx >= NL * HID) return;
  int l = idx >> 7, n = idx & 127;
  float s = ldf(gb, idx, bf);
  long lb = (long)l * 16384;
  for (int k = 0; k < 128; k++)
    s += ldf(cbias, (long)l * 128 + k, bf) * ldf(gW, lb + (long)k * 128 + n, bf);
  bprime[idx] = s;
}

// ---------------- weight prep: edge MLP W1 -> bf16 W1t[256 cols][32 K] ------
// k<16: W1; k==16: b1 (MFMA bias-fold); k>16: 0.
__global__ __launch_bounds__(256) void prep_edge_w(const void* __restrict__ mW1,
                                                   const void* __restrict__ mb1,
                                                   unsigned short* __restrict__ W1t,
                                                   const int* __restrict__ flag) {
  bool bf = *flag != 0;
  int idx = blockIdx.x * 256 + threadIdx.x;  // 256*32
  if (idx >= 256 * 32) return;
  int col = idx >> 5, k = idx & 31;
  float v = 0.f;
  if (k < EDIM) v = ldf(mW1, (long)(col >> 6) * (EDIM * EHID) + (long)k * EHID + (col & 63), bf);
  else if (k == EDIM) v = ldf(mb1, col, bf);
  W1t[idx] = f2bf_bits(v);
}

// ---------------- weight prep: tail (MLP+predictor) -> bf16 [N][Kp], K-pad --
__global__ __launch_bounds__(256) void prep_tail(
    const void* __restrict__ mlpW0, const void* __restrict__ mlpW1,
    const void* __restrict__ mlpW2, const void* __restrict__ mlpW3,
    const void* __restrict__ predW0, const void* __restrict__ predW1,
    unsigned short* __restrict__ T, const int* __restrict__ flag) {
  bool bf = *flag != 0;
  int idx = blockIdx.x * 256 + threadIdx.x;
  const void* src; int N, Kp, Ksrc, off;
  if      (idx < 65536)  { src = mlpW0;  N = 256; Kp = 256; Ksrc = 200; off = 0; }
  else if (idx < 131072) { src = mlpW1;  N = 256; Kp = 256; Ksrc = 256; off = 65536; }
  else if (idx < 196608) { src = mlpW2;  N = 256; Kp = 256; Ksrc = 256; off = 131072; }
  else if (idx < 229376) { src = mlpW3;  N = 128; Kp = 256; Ksrc = 256; off = 196608; }
  else if (idx < 360448) { src = predW0; N = 512; Kp = 256; Ksrc = 256; off = 229376; }
  else if (idx < 622592) { src = predW1; N = 512; Kp = 512; Ksrc = 512; off = 360448; }
  else return;
  int rem = idx - off;
  int n = rem / Kp, k = rem % Kp;
  float v = (k < Ksrc) ? ldf(src, (long)k * N + n, bf) : 0.f;
  T[idx] = f2bf_bits(v);
}

// ---------------- CSR build: histogram / 3-phase scan / fill ----------------
__global__ __launch_bounds__(256) void count_kernel(const int* __restrict__ ei,
                                                    int* __restrict__ cnt) {
  int e = blockIdx.x * 256 + threadIdx.x;
  if (e >= EE) return;
  int c = ei[EE + e];
  c = min(max(c, 0), NN - 1);
  atomicAdd(&cnt[c], 1);
}

__global__ __launch_bounds__(256) void scan_phase1(const int* __restrict__ cnt,
                                                   int* __restrict__ bsum) {
  __shared__ int red[256];
  int tid = threadIdx.x;
  int i = blockIdx.x * 256 + tid;
  red[tid] = (i < NN) ? cnt[i] : 0;
  __syncthreads();
  for (int off = 128; off > 0; off >>= 1) {
    if (tid < off) red[tid] += red[tid + off];
    __syncthreads();
  }
  if (tid == 0) bsum[blockIdx.x] = red[0];
}

__global__ __launch_bounds__(256) void scan_phase2(int* __restrict__ bsum,
                                                   int* __restrict__ offs) {
  __shared__ int buf[256];
  int tid = threadIdx.x;
  int v = (tid < SCAN_B) ? bsum[tid] : 0;
  buf[tid] = v;
  __syncthreads();
  for (int off = 1; off < 256; off <<= 1) {
    int t = (tid >= off) ? buf[tid - off] : 0;
    __syncthreads();
    buf[tid] += t;
    __syncthreads();
  }
  if (tid < SCAN_B) bsum[tid] = buf[tid] - v;  // exclusive block offsets
  if (tid == 255) offs[NN] = buf[255];
}

__global__ __launch_bounds__(256) void scan_phase3(const int* __restrict__ cnt,
                                                   const int* __restrict__ bsum,
                                                   int* __restrict__ offs) {
  __shared__ int buf[256];
  int tid = threadIdx.x;
  int i = blockIdx.x * 256 + tid;
  int v = (i < NN) ? cnt[i] : 0;
  buf[tid] = v;
  __syncthreads();
  for (int off = 1; off < 256; off <<= 1) {
    int t = (tid >= off) ? buf[tid - off] : 0;
    __syncthreads();
    buf[tid] += t;
    __syncthreads();
  }
  if (i < NN) offs[i] = bsum[blockIdx.x] + buf[tid] - v;
}

__global__ __launch_bounds__(256) void fill_kernel(const int* __restrict__ ei,
                                                   const int* __restrict__ offs,
                                                   int* __restrict__ cursor,
                                                   int2* __restrict__ csr_se) {
  int e = blockIdx.x * 256 + threadIdx.x;
  if (e >= EE) return;
  int c = ei[EE + e];
  c = min(max(c, 0), NN - 1);
  int pos = offs[c] + atomicAdd(&cursor[c], 1);
  pos = min(max(pos, 0), EE - 1);
  csr_se[pos] = make_int2(ei[e], e);
}

// ---------------- edge-gate MLP via MFMA: ORIGINAL edge order ---------------
__global__ __launch_bounds__(256) void edge_mlp_mfma(
    const void* __restrict__ eattr, const unsigned short* __restrict__ W1t,
    const void* __restrict__ mW2, const void* __restrict__ mb2,
    float* __restrict__ w_all4, const int* __restrict__ flag) {
  bool bf = *flag != 0;
  int tid = threadIdx.x;
  int wave = tid >> 6, lane = tid & 63;
  int l15 = lane & 15, quad = lane >> 4;

  bf16x8 bfrag[16];
#pragma unroll
  for (int t = 0; t < 16; t++)
    bfrag[t] = *reinterpret_cast<const bf16x8*>(&W1t[(t * 16 + l15) * 32 + quad * 8]);

  float w2v[16];
#pragma unroll
  for (int t = 0; t < 16; t++) w2v[t] = ldf(mW2, t * 16 + l15, bf);
  float b2v0 = ldf(mb2, 0, bf), b2v1 = ldf(mb2, 1, bf);
  float b2v2 = ldf(mb2, 2, bf), b2v3 = ldf(mb2, 3, bf);
  float b2 = b2v0;
  b2 = (l15 == 1) ? b2v1 : b2;
  b2 = (l15 == 2) ? b2v2 : b2;
  b2 = (l15 == 3) ? b2v3 : b2;
  bool o1 = (l15 & 1) != 0;
  bool o2 = (l15 & 2) != 0;

  int ebase = blockIdx.x * 512 + wave * 128;
#pragma unroll 1
  for (int f = 0; f < 8; f++) {
    int fbase = ebase + f * 16;
    if (fbase < EE) {  // EE%16==0 -> whole fragment in-bounds
      long erow = fbase + l15;
      bf16x8 a = (bf16x8){0, 0, 0, 0, 0, 0, 0, 0};
      if (quad < 2) {
        if (bf) {
          uint4 v = *reinterpret_cast<const uint4*>((const bf16*)eattr + erow * EDIM + quad * 8);
          a = *reinterpret_cast<bf16x8*>(&v);
        } else {
          const float4* p =
              reinterpret_cast<const float4*>((const float*)eattr + erow * EDIM + quad * 8);
          float4 v0 = p[0], v1 = p[1];
          a[0] = (short)f2bf_bits(v0.x); a[1] = (short)f2bf_bits(v0.y);
          a[2] = (short)f2bf_bits(v0.z); a[3] = (short)f2bf_bits(v0.w);
          a[4] = (short)f2bf_bits(v1.x); a[5] = (short)f2bf_bits(v1.y);
          a[6] = (short)f2bf_bits(v1.z); a[7] = (short)f2bf_bits(v1.w);
        }
      }
      if (quad == 2) a[0] = (short)0x3F80;  // k=16 element = bf16(1.0): adds b1
      float s00 = 0.f, s01 = 0.f, s02 = 0.f, s03 = 0.f;
      float s10 = 0.f, s11 = 0.f, s12 = 0.f, s13 = 0.f;
      float s20 = 0.f, s21 = 0.f, s22 = 0.f, s23 = 0.f;
      float s30 = 0.f, s31 = 0.f, s32 = 0.f, s33 = 0.f;
#define DO_T(T, S0, S1, S2, S3)                                               \
  {                                                                           \
    f32x4 acc = __builtin_amdgcn_mfma_f32_16x16x32_bf16(                      \
        a, bfrag[T], (f32x4){0.f, 0.f, 0.f, 0.f}, 0, 0, 0);                   \
    S0 += fmaxf(acc.x, 0.f) * w2v[T];                                         \
    S1 += fmaxf(acc.y, 0.f) * w2v[T];                                         \
    S2 += fmaxf(acc.z, 0.f) * w2v[T];                                         \
    S3 += fmaxf(acc.w, 0.f) * w2v[T];                                         \
  }
      DO_T(0,  s00, s01, s02, s03) DO_T(1,  s00, s01, s02, s03)
      DO_T(2,  s00, s01, s02, s03) DO_T(3,  s00, s01, s02, s03)
      DO_T(4,  s10, s11, s12, s13) DO_T(5,  s10, s11, s12, s13)
      DO_T(6,  s10, s11, s12, s13) DO_T(7,  s10, s11, s12, s13)
      DO_T(8,  s20, s21, s22, s23) DO_T(9,  s20, s21, s22, s23)
      DO_T(10, s20, s21, s22, s23) DO_T(11, s20, s21, s22, s23)
      DO_T(12, s30, s31, s32, s33) DO_T(13, s30, s31, s32, s33)
      DO_T(14, s30, s31, s32, s33) DO_T(15, s30, s31, s32, s33)
#undef DO_T
#define RS_STEP1(AR, S0R, S1R) \
  float AR = (o1 ? S1R : S0R) + __shfl_xor(o1 ? S0R : S1R, 1);
      RS_STEP1(a0, s00, s10)
      RS_STEP1(a1, s01, s11)
      RS_STEP1(a2, s02, s12)
      RS_STEP1(a3, s03, s13)
      RS_STEP1(bb0, s20, s30)
      RS_STEP1(bb1, s21, s31)
      RS_STEP1(bb2, s22, s32)
      RS_STEP1(bb3, s23, s33)
#undef RS_STEP1
      float c0 = (o2 ? bb0 : a0) + __shfl_xor(o2 ? a0 : bb0, 2);
      float c1 = (o2 ? bb1 : a1) + __shfl_xor(o2 ? a1 : bb1, 2);
      float c2 = (o2 ? bb2 : a2) + __shfl_xor(o2 ? a2 : bb2, 2);
      float c3 = (o2 ? bb3 : a3) + __shfl_xor(o2 ? a3 : bb3, 2);
      c0 += __shfl_xor(c0, 4); c1 += __shfl_xor(c1, 4);
      c2 += __shfl_xor(c2, 4); c3 += __shfl_xor(c3, 4);
      c0 += __shfl_xor(c0, 8); c1 += __shfl_xor(c1, 8);
      c2 += __shfl_xor(c2, 8); c3 += __shfl_xor(c3, 8);
      if (l15 < NL) {
        float g0 = 1.f / (1.f + __expf(-(c0 + b2)));
        float g1 = 1.f / (1.f + __expf(-(c1 + b2)));
        float g2 = 1.f / (1.f + __expf(-(c2 + b2)));
        float g3 = 1.f / (1.f + __expf(-(c3 + b2)));
        w_all4[(size_t)(fbase + quad * 4 + 0) * 4 + l15] = g0;
        w_all4[(size_t)(fbase + quad * 4 + 1) * 4 + l15] = g1;
        w_all4[(size_t)(fbase + quad * 4 + 2) * 4 + l15] = g2;
        w_all4[(size_t)(fbase + quad * 4 + 3) * 4 + l15] = g3;
      }
    }
  }
}

// ---------------- gather gates into CSR order -------------------------------
__global__ __launch_bounds__(256) void csr_gather(const int2* __restrict__ csr_se,
                                                  const float* __restrict__ w_all4,
                                                  float* __restrict__ csr_val) {
  int k = blockIdx.x * 256 + threadIdx.x;
  if (k >= EE) return;
  int eid = csr_se[k].y;
  eid = min(max(eid, 0), EE - 1);
  float4 w = reinterpret_cast<const float4*>(w_all4)[eid];
  csr_val[k] = w.x;
  csr_val[(size_t)EE + k] = w.y;
  csr_val[2 * (size_t)EE + k] = w.z;
  csr_val[3 * (size_t)EE + k] = w.w;
}

// ---------------- degree / dinv per layer (interleaved float4 out) ----------
__global__ __launch_bounds__(256) void deg_kernel(const int* __restrict__ offs,
                                                  const float* __restrict__ csr_val,
                                                  float* __restrict__ dinv4) {
  int n = blockIdx.x * 256 + threadIdx.x;
  if (n >= NN) return;
  int s = offs[n], e = offs[n + 1];
  float d0 = 1.f, d1 = 1.f, d2 = 1.f, d3 = 1.f;  // self-loop weight 1.0
  for (int k = s; k < e; k++) {
    d0 += csr_val[k];
    d1 += csr_val[EE + k];
    d2 += csr_val[2 * (size_t)EE + k];
    d3 += csr_val[3 * (size_t)EE + k];
  }
  float4 o;
  o.x = rsqrtf(d0); o.y = rsqrtf(d1); o.z = rsqrtf(d2); o.w = rsqrtf(d3);
  reinterpret_cast<float4*>(dinv4)[n] = o;
}

// csr_val[l][k] *= dinv_l[src_k]
__global__ __launch_bounds__(256) void csr_scale_kernel(const int2* __restrict__ csr_se,
                                                        const float* __restrict__ dinv4,
                                                        float* __restrict__ csr_val) {
  int k = blockIdx.x * 256 + threadIdx.x;
  if (k >= EE) return;
  int s = csr_se[k].x;
  s = min(max(s, 0), NN - 1);
  float4 d = reinterpret_cast<const float4*>(dinv4)[s];
  csr_val[k] *= d.x;
  csr_val[(size_t)EE + k] *= d.y;
  csr_val[2 * (size_t)EE + k] *= d.z;
  csr_val[3 * (size_t)EE + k] *= d.w;
}

// ---------------- node GEMM via MFMA: bf16 in/out, f32 bias -----------------
__global__ __launch_bounds__(256) void gemm_nodes_bf16(
    const unsigned short* __restrict__ A16, const unsigned short* __restrict__ Wt,
    const float* __restrict__ bias, unsigned short* __restrict__ out16,
    int relu) {
  __shared__ alignas(16) unsigned short sA[64 * 136];
  __shared__ alignas(16) unsigned short sW[128 * 136];
  int tid = threadIdx.x;
  int rbase = blockIdx.x * 64;

#pragma unroll
  for (int p = 0; p < 8; p++) {
    int idx8 = p * 256 + tid;
    int n = idx8 >> 4, kc = idx8 & 15;
    uint4 v = reinterpret_cast<const uint4*>(Wt)[idx8];
    *reinterpret_cast<uint4*>(&sW[n * 136 + kc * 8]) = v;
  }
#pragma unroll
  for (int p = 0; p < 4; p++) {
    int idx8 = p * 256 + tid;
    int m = idx8 >> 4, kc = idx8 & 15;
    int row = rbase + m;
    uint4 v = make_uint4(0u, 0u, 0u, 0u);
    if (row < NN)
      v = *reinterpret_cast<const uint4*>(&A16[(size_t)row * HID + kc * 8]);
    *reinterpret_cast<uint4*>(&sA[m * 136 + kc * 8]) = v;
  }
  __syncthreads();

  int wave = tid >> 6, lane = tid & 63;
  int l15 = lane & 15, quad = lane >> 4;
  int mstrip = wave * 16;

  f32x4 acc[8];
#pragma unroll
  for (int t = 0; t < 8; t++) acc[t] = (f32x4){0.f, 0.f, 0.f, 0.f};

#pragma unroll
  for (int ks = 0; ks < 4; ks++) {
    int k0 = ks * 32 + quad * 8;
    bf16x8 a = *reinterpret_cast<const bf16x8*>(&sA[(mstrip + l15) * 136 + k0]);
#pragma unroll
    for (int t = 0; t < 8; t++) {
      bf16x8 b = *reinterpret_cast<const bf16x8*>(&sW[(t * 16 + l15) * 136 + k0]);
      acc[t] = __builtin_amdgcn_mfma_f32_16x16x32_bf16(a, b, acc[t], 0, 0, 0);
    }
  }

#pragma unroll
  for (int t = 0; t < 8; t++) {
    int n = t * 16 + l15;
    float bv = bias ? bias[n] : 0.f;
#pragma unroll
    for (int r = 0; r < 4; r++) {
      int row = rbase + mstrip + quad * 4 + r;
      if (row < NN) {
        float o = acc[t][r] + bv;
        if (relu) o = fmaxf(o, 0.f);
        out16[(size_t)row * HID + n] = f2bf_bits(o);
      }
    }
  }
}

// ---------------- tail GEMM via MFMA ----------------------------------------
__global__ __launch_bounds__(256) void gemm_tail_mfma(
    const float* __restrict__ A, int lda, const unsigned short* __restrict__ Wt,
    int Kp, const void* __restrict__ bias, float* __restrict__ outp, int ldo,
    int relu, const int* __restrict__ flag) {
  __shared__ alignas(16) unsigned short sA[64 * 264];
  __shared__ alignas(16) unsigned short sW[64 * 264];
  int tid = threadIdx.x;
  int rbase = blockIdx.x * 64;
  int nbase = blockIdx.y * 64;
  int wave = tid >> 6, lane = tid & 63;
  int l15 = lane & 15, quad = lane >> 4;
  int mstrip = wave * 16;

  f32x4 acc[4];
#pragma unroll
  for (int t = 0; t < 4; t++) acc[t] = (f32x4){0.f, 0.f, 0.f, 0.f};

  for (int kc = 0; kc < Kp; kc += 256) {
#pragma unroll 4
    for (int p = 0; p < 16; p++) {
      int idx = p * 1024 + tid * 4;
      int m = idx >> 8, k = idx & 255;
      float4 v = *reinterpret_cast<const float4*>(&A[(size_t)(rbase + m) * lda + kc + k]);
      ushort4 b;
      b.x = f2bf_bits(v.x); b.y = f2bf_bits(v.y);
      b.z = f2bf_bits(v.z); b.w = f2bf_bits(v.w);
      *reinterpret_cast<ushort4*>(&sA[m * 264 + k]) = b;
    }
#pragma unroll 4
    for (int p = 0; p < 8; p++) {
      int idx8 = p * 256 + tid;
      int n = idx8 >> 5, kk = (idx8 & 31) * 8;
      uint4 v = *reinterpret_cast<const uint4*>(&Wt[(size_t)(nbase + n) * Kp + kc + kk]);
      *reinterpret_cast<uint4*>(&sW[n * 264 + kk]) = v;
    }
    __syncthreads();
#pragma unroll
    for (int ks = 0; ks < 8; ks++) {
      int k0 = ks * 32 + quad * 8;
      bf16x8 a = *reinterpret_cast<const bf16x8*>(&sA[(mstrip + l15) * 264 + k0]);
#pragma unroll
      for (int nt = 0; nt < 4; nt++) {
        bf16x8 b = *reinterpret_cast<const bf16x8*>(&sW[(nt * 16 + l15) * 264 + k0]);
        acc[nt] = __builtin_amdgcn_mfma_f32_16x16x32_bf16(a, b, acc[nt], 0, 0, 0);
      }
    }
    __syncthreads();
  }

  bool bf = *flag != 0;
#pragma unroll
  for (int nt = 0; nt < 4; nt++) {
    int col = nbase + nt * 16 + l15;
    float bv = ldf(bias, col, bf);
#pragma unroll
    for (int r = 0; r < 4; r++) {
      int row = rbase + mstrip + quad * 4 + r;
      float o = acc[nt][r] + bv;
      if (relu) o = fmaxf(o, 0.f);
      outp[(size_t)row * ldo + col] = o;
    }
  }
}

// ---------------- aggregation (round-14 form; gathers h16; no bias) ---------
// out16[n] = dn*(sum_k val_k*h16[src_k]) + dn^2*h16[n]
__global__ __launch_bounds__(128) void aggregate_kernel(
    const unsigned short* __restrict__ h16, const int* __restrict__ offs,
    const int2* __restrict__ csr_se, const float* __restrict__ csr_val,
    const float* __restrict__ dinv4, int layer,
    unsigned short* __restrict__ out16) {
  int n = blockIdx.x;
  int c = threadIdx.x;
  __shared__ int s_src[128];
  __shared__ float s_val[128];
  int start = offs[n], end = offs[n + 1];
  float acc = 0.f;
  for (int base = start; base < end; base += 128) {
    int k = base + c;
    if (k < end) {
      s_src[c] = min(max(csr_se[k].x, 0), NN - 1);
      s_val[c] = csr_val[k];
    }
    __syncthreads();
    int m = min(128, end - base);
    for (int j = 0; j < m; j++)
      acc = fmaf(s_val[j], bfl((unsigned)h16[(size_t)s_src[j] * HID + c]), acc);
    __syncthreads();
  }
  float dn = dinv4[(size_t)n * 4 + layer];
  float selfv = bfl((unsigned)h16[(size_t)n * HID + c]);
  out16[(size_t)n * HID + c] = f2bf_bits(dn * acc + dn * dn * selfv);
}

// ---------------- mean pool, 2-phase (bf16 input) ---------------------------
__global__ __launch_bounds__(128) void pool_partial(const unsigned short* __restrict__ h16,
                                                    const int* __restrict__ batch,
                                                    float* __restrict__ part) {
  int g = blockIdx.x, chunk = blockIdx.y, c = threadIdx.x;
  int lo = 0, hi = NN;
  while (lo < hi) { int mid = (lo + hi) >> 1; if (batch[mid] < g) lo = mid + 1; else hi = mid; }
  int start = lo;
  hi = NN;
  while (lo < hi) { int mid = (lo + hi) >> 1; if (batch[mid] < g + 1) lo = mid + 1; else hi = mid; }
  int end = lo;
  int len = end - start;
  int per = (len + PCH - 1) / PCH;
  int s = start + chunk * per;
  int e = min(s + per, end);
  float sum = 0.f;
  for (int n = s; n < e; n++) sum += bfl((unsigned)h16[(size_t)n * HID + c]);
  part[((size_t)g * PCH + chunk) * HID + c] = sum;
}

__global__ __launch_bounds__(128) void pool_combine(const float* __restrict__ part,
                                                    const int* __restrict__ batch,
                                                    float* __restrict__ cat) {
  int g = blockIdx.x, c = threadIdx.x;
  int lo = 0, hi = NN;
  while (lo < hi) { int mid = (lo + hi) >> 1; if (batch[mid] < g) lo = mid + 1; else hi = mid; }
  int start = lo;
  hi = NN;
  while (lo < hi) { int mid = (lo + hi) >> 1; if (batch[mid] < g + 1) lo = mid + 1; else hi = mid; }
  int end = lo;
  float s = 0.f;
#pragma unroll
  for (int k = 0; k < PCH; k++) s += part[((size_t)g * PCH + k) * HID + c];
  float cntf = (float)(end - start);
  cat[(size_t)g * PIN + c] = s / fmaxf(cntf, 1.f);
}

// ---------------- final [G,512] @ [512,1] + b -> out ------------------------
__global__ __launch_bounds__(64) void final_kernel(const float* __restrict__ A,
                                                   const void* __restrict__ W,
                                                   const void* __restrict__ b,
                                                   void* __restrict__ outp,
                                                   const int* __restrict__ flag) {
  bool bf = *flag != 0;
  int g = blockIdx.x, lane = threadIdx.x;
  float s = 0.f;
  for (int k = lane; k < PH; k += 64) s = fmaf(A[(size_t)g * PH + k], ldf(W, k, bf), s);
#pragma unroll
  for (int off = 32; off > 0; off >>= 1) s += __shfl_down(s, off);
  if (lane == 0) {
    float r = s + ldf(b, 0, bf);
    if (bf) ((bf16*)outp)[g] = __float2bfloat16(r);
    else    ((float*)outp)[g] = r;
  }
}

// ---------------------------------------------------------------------------
extern "C" void kernel_launch(void* const* d_in, const int* in_sizes, int n_in,
                              void* d_out, int out_size, void* d_ws, size_t ws_size,
                              hipStream_t stream) {
  const void* x      = d_in[0];
  const int*  ei     = (const int*)d_in[1];
  const void* eattr  = d_in[2];
  const int*  batch  = (const int*)d_in[3];
  const void* molf   = d_in[4];
  const void* lin_W  = d_in[5];
  const void* mW1    = d_in[6];
  const void* mb1    = d_in[7];
  const void* mW2    = d_in[8];
  const void* mb2    = d_in[9];
  const void* cbias  = d_in[10];
  const void* gW     = d_in[11];
  const void* gb     = d_in[12];
  const void* mlpW0  = d_in[13];
  const void* mlpb0  = d_in[14];
  const void* mlpW1  = d_in[15];
  const void* mlpb1  = d_in[16];
  const void* mlpW2  = d_in[17];
  const void* mlpb2  = d_in[18];
  const void* mlpW3  = d_in[19];
  const void* mlpb3  = d_in[20];
  const void* predW0 = d_in[21];
  const void* predb0 = d_in[22];
  const void* predW1 = d_in[23];
  const void* predb1 = d_in[24];
  const void* outW   = d_in[25];
  const void* outb   = d_in[26];

  char* base = (char*)d_ws;
  size_t off = 0;
  auto alloc = [&](size_t bytes) -> char* {
    char* p = base + off;
    off = (off + bytes + 255) & ~(size_t)255;
    return p;
  };
  unsigned short* h16  = (unsigned short*)alloc((size_t)NN * HID * 2);
  unsigned short* t16  = (unsigned short*)alloc((size_t)NN * HID * 2);
  float* dinv4    = (float*)alloc((size_t)NN * 4 * 4);
  int*   cnt      = (int*)alloc((size_t)NN * 4);
  int*   offs     = (int*)alloc((size_t)(NN + 1) * 4);
  int*   cursor   = (int*)alloc((size_t)NN * 4);
  int*   bsum     = (int*)alloc((size_t)256 * 4);
  int2*  csr_se   = (int2*)alloc((size_t)EE * 8);
  float* csr_val  = (float*)alloc((size_t)NL * EE * 4);
  float* w_all4   = (float*)alloc((size_t)EE * 4 * 4);
  unsigned short* Wt    = (unsigned short*)alloc((size_t)NL * HID * HID * 2);
  float* bprime   = (float*)alloc((size_t)NL * HID * 4);
  unsigned short* tailW = (unsigned short*)alloc((size_t)622592 * 2);
  unsigned short* edgeW = (unsigned short*)alloc((size_t)256 * 32 * 2);
  int*   flag     = (int*)alloc(256);
  float* part     = (float*)alloc((size_t)GG * PCH * HID * 4);
  float* molf32   = (float*)alloc((size_t)GG * 256 * 4);
  float* m0       = (float*)alloc((size_t)GG * MH * 4);
  float* m1       = (float*)alloc((size_t)GG * MH * 4);
  float* cat      = (float*)alloc((size_t)GG * PIN * 4);
  float* p0       = (float*)alloc((size_t)GG * PH * 4);
  float* p1       = (float*)alloc((size_t)GG * PH * 4);

  hipMemsetAsync(cnt, 0, (size_t)NN * 4, stream);
  hipMemsetAsync(cursor, 0, (size_t)NN * 4, stream);
  hipMemsetAsync(molf32, 0, (size_t)GG * 256 * 4, stream);

  // dtype probe first — everything downstream branches on it
  probe_kernel<<<1, 64, 0, stream>>>((const unsigned short*)x, flag);

  // weight prep (fused layer weights + tail + edge)
  prep_fused_w<<<256, 256, 0, stream>>>(lin_W, gW, Wt, flag);
  prep_fused_b<<<NL, 128, 0, stream>>>(cbias, gW, gb, bprime, flag);
  prep_tail<<<(622592 + 255) / 256, 256, 0, stream>>>(mlpW0, mlpW1, mlpW2, mlpW3,
                                                      predW0, predW1, tailW, flag);
  prep_edge_w<<<32, 256, 0, stream>>>(mW1, mb1, edgeW, flag);

  // x -> bf16 layer state
  {
    int n8 = NN * HID / 8;
    cvt_to_bf16<<<(n8 + 255) / 256, 256, 0, stream>>>(x, h16, n8, flag);
  }
  // edge gates (MFMA, ORIGINAL order, 8 frags/wave, b1 folded)
  edge_mlp_mfma<<<(EE + 511) / 512, 256, 0, stream>>>(eattr, edgeW, mW2, mb2,
                                                      w_all4, flag);
  // CSR build (3-phase parallel scan)
  count_kernel<<<(EE + 255) / 256, 256, 0, stream>>>(ei, cnt);
  scan_phase1<<<SCAN_B, 256, 0, stream>>>(cnt, bsum);
  scan_phase2<<<1, 256, 0, stream>>>(bsum, offs);
  scan_phase3<<<SCAN_B, 256, 0, stream>>>(cnt, bsum, offs);
  fill_kernel<<<(EE + 255) / 256, 256, 0, stream>>>(ei, offs, cursor, csr_se);
  // permute gates to CSR order, degrees, scaling
  csr_gather<<<(EE + 255) / 256, 256, 0, stream>>>(csr_se, w_all4, csr_val);
  deg_kernel<<<(NN + 255) / 256, 256, 0, stream>>>(offs, csr_val, dinv4);
  csr_scale_kernel<<<(EE + 255) / 256, 256, 0, stream>>>(csr_se, dinv4, csr_val);

  // GCN layers (fused): aggregate(h16)->t16; gemm(t16, W'_l, b'_l, relu)->h16
  const int gemm_blocks = (NN + 63) / 64;  // 782
  for (int l = 0; l < NL; l++) {
    aggregate_kernel<<<NN, 128, 0, stream>>>(h16, offs, csr_se,
                                             csr_val + (size_t)l * EE, dinv4, l, t16);
    gemm_nodes_bf16<<<gemm_blocks, 256, 0, stream>>>(
        t16, Wt + (size_t)l * HID * HID, bprime + (size_t)l * HID, h16, 1);
  }

  // pooling -> cat[:, 0:128]  (2-phase, bf16 input)
  pool_partial<<<dim3(GG, PCH), 128, 0, stream>>>(h16, batch, part);
  pool_combine<<<GG, 128, 0, stream>>>(part, batch, cat);

  // molecular MLP -> cat[:, 128:256]  (MFMA tail, K-padded weights)
  cvt_molf<<<(GG * 50 + 255) / 256, 256, 0, stream>>>(molf, molf32, flag);
  gemm_tail_mfma<<<dim3(4, 4), 256, 0, stream>>>(molf32, 256, tailW + 0,      256, mlpb0, m0, 256, 1, flag);
  gemm_tail_mfma<<<dim3(4, 4), 256, 0, stream>>>(m0,     256, tailW + 65536,  256, mlpb1, m1, 256, 1, flag);
  gemm_tail_mfma<<<dim3(4, 4), 256, 0, stream>>>(m1,     256, tailW + 131072, 256, mlpb2, m0, 256, 1, flag);
  gemm_tail_mfma<<<dim3(4, 2), 256, 0, stream>>>(m0,     256, tailW + 196608, 256, mlpb3, cat + MOUT, 256, 1, flag);

  // predictor
  gemm_tail_mfma<<<dim3(4, 8), 256, 0, stream>>>(cat, 256, tailW + 229376, 256, predb0, p0, 512, 1, flag);
  gemm_tail_mfma<<<dim3(4, 8), 256, 0, stream>>>(p0,  512, tailW + 360448, 512, predb1, p1, 512, 1, flag);
  final_kernel<<<GG, 64, 0, stream>>>(p1, outW, outb, d_out, flag);
}

// Round 17
// 578.719 us; speedup vs baseline: 1.2087x; 1.1070x over previous
//
#include <hip/hip_runtime.h>
#include <hip/hip_bf16.h>

// ---------------------------------------------------------------------------
// PDNConv GNN, MI355X round 17.
// Round-16: linear fusion landed (699->641us). aggregate x4 (45us each) now
// dominates. Rework (single change): one wave per node; lane=(grp 0..3, c16
// 0..15); each lane gathers 16B (uint4) so a wave-load covers 4 rows at once
// (4 coalesced 256B transactions); per-group chains = deg/4; group combine
// via 2 shfl_xor steps (NO extra barriers — the round-15 mistake); 8 NAMED
// scalar accumulators (round-9/10 lesson). Everything else = round 16.
// ---------------------------------------------------------------------------

#define NN 50000
#define EE 600000
#define GG 256
#define HID 128
#define EDIM 16
#define EHID 64
#define NL 4
#define MIN_F 200
#define MH 256
#define MOUT 128
#define PH 512
#define PIN 256
#define SCAN_B 196  // ceil(NN/256)
#define PCH 8       // pooling chunks per graph

typedef __hip_bfloat16 bf16;
typedef __attribute__((ext_vector_type(8))) short bf16x8;
typedef __attribute__((ext_vector_type(4))) float f32x4;

__device__ __forceinline__ float bfl(unsigned u) { return __uint_as_float(u << 16); }
__device__ __forceinline__ float bfh(unsigned u) { return __uint_as_float(u & 0xffff0000u); }
__device__ __forceinline__ float b2f(bf16 x) { return __bfloat162float(x); }
__device__ __forceinline__ float ldf(const void* p, long i, bool bf) {
  return bf ? __bfloat162float(((const bf16*)p)[i]) : ((const float*)p)[i];
}
__device__ __forceinline__ unsigned short f2bf_bits(float v) {
  bf16 h = __float2bfloat16(v);
  return *reinterpret_cast<unsigned short*>(&h);
}

// ---------------- dtype probe ------------------------------------------------
__global__ void probe_kernel(const unsigned short* __restrict__ xs, int* flag) {
  if (threadIdx.x == 0 && blockIdx.x == 0) {
    int sane = 0;
    for (int i = 0; i < 128; i++) {
      unsigned e = (xs[i] >> 7) & 0xFF;
      if (e >= 96 && e <= 159) sane++;
    }
    *flag = (sane >= 112) ? 1 : 0;  // 1 = bf16 inputs
  }
}

// ---------------- input -> bf16 conversion (8 elems/thread) -----------------
__global__ __launch_bounds__(256) void cvt_to_bf16(const void* __restrict__ in,
                                                   unsigned short* __restrict__ outp,
                                                   int n8, const int* __restrict__ flag) {
  bool bf = *flag != 0;
  int i = blockIdx.x * 256 + threadIdx.x;
  if (i >= n8) return;
  if (bf) {
    reinterpret_cast<uint4*>(outp)[i] = reinterpret_cast<const uint4*>(in)[i];
  } else {
    const float4* p = reinterpret_cast<const float4*>(in) + (size_t)i * 2;
    float4 v0 = p[0], v1 = p[1];
    ushort4 a, b;
    a.x = f2bf_bits(v0.x); a.y = f2bf_bits(v0.y);
    a.z = f2bf_bits(v0.z); a.w = f2bf_bits(v0.w);
    b.x = f2bf_bits(v1.x); b.y = f2bf_bits(v1.y);
    b.z = f2bf_bits(v1.z); b.w = f2bf_bits(v1.w);
    reinterpret_cast<ushort4*>(outp)[i * 2] = a;
    reinterpret_cast<ushort4*>(outp)[i * 2 + 1] = b;
  }
}

// ---------------- mol_features [G,200] -> padded f32 [G,256] ----------------
__global__ __launch_bounds__(256) void cvt_molf(const void* __restrict__ in,
                                                float* __restrict__ outp,
                                                const int* __restrict__ flag) {
  bool bf = *flag != 0;
  int i = blockIdx.x * 256 + threadIdx.x;  // GG*50
  if (i >= GG * 50) return;
  int row = i / 50, c4 = (i % 50) * 4;
  float4 v;
  if (bf) {
    const unsigned short* p = (const unsigned short*)in + (size_t)row * MIN_F + c4;
    uint2 u = *reinterpret_cast<const uint2*>(p);
    v.x = bfl(u.x); v.y = bfh(u.x); v.z = bfl(u.y); v.w = bfh(u.y);
  } else {
    v = *reinterpret_cast<const float4*>((const float*)in + (size_t)row * MIN_F + c4);
  }
  *reinterpret_cast<float4*>(&outp[(size_t)row * 256 + c4]) = v;
}

// ---------------- weight prep: fused W'_l = linW_l @ gW_l -> bf16 [n][k] ----
__global__ __launch_bounds__(256) void prep_fused_w(const void* __restrict__ lin_W,
                                                    const void* __restrict__ gW,
                                                    unsigned short* __restrict__ Wt,
                                                    const int* __restrict__ flag) {
  bool bf = *flag != 0;
  int idx = blockIdx.x * 256 + threadIdx.x;  // 0 .. 4*16384-1
  if (idx >= 4 * 16384) return;
  int l = idx >> 14;
  int rem = idx & 16383;
  int n = rem >> 7, k = rem & 127;  // Wt[n][k] = W'[k][n]
  float s = 0.f;
  long lb = (long)l * 16384;
  for (int m = 0; m < 128; m++)
    s += ldf(lin_W, lb + (long)k * 128 + m, bf) * ldf(gW, lb + (long)m * 128 + n, bf);
  Wt[idx] = f2bf_bits(s);
}

// b'_l[n] = gb_l[n] + sum_k cbias_l[k] * gW_l[k][n]   (f32)
__global__ __launch_bounds__(128) void prep_fused_b(const void* __restrict__ cbias,
                                                    const void* __restrict__ gW,
                                                    const void* __restrict__ gb,
                                                    float* __restrict__ bprime,
                                                    const int* __restrict__ flag) {
  bool bf = *flag != 0;
  int idx = blockIdx.x * 128 + threadIdx.x;  // 0 .. 4*128-1
  if (idx >= NL * HID) return;
  int l = idx >> 7, n = idx & 127;
  float s = ldf(gb, idx, bf);
  long lb = (long)l * 16384;
  for (int k = 0; k < 128; k++)
    s += ldf(cbias, (long)l * 128 + k, bf) * ldf(gW, lb + (long)k * 128 + n, bf);
  bprime[idx] = s;
}

// ---------------- weight prep: edge MLP W1 -> bf16 W1t[256 cols][32 K] ------
// k<16: W1; k==16: b1 (MFMA bias-fold); k>16: 0.
__global__ __launch_bounds__(256) void prep_edge_w(const void* __restrict__ mW1,
                                                   const void* __restrict__ mb1,
                                                   unsigned short* __restrict__ W1t,
                                                   const int* __restrict__ flag) {
  bool bf = *flag != 0;
  int idx = blockIdx.x * 256 + threadIdx.x;  // 256*32
  if (idx >= 256 * 32) return;
  int col = idx >> 5, k = idx & 31;
  float v = 0.f;
  if (k < EDIM) v = ldf(mW1, (long)(col >> 6) * (EDIM * EHID) + (long)k * EHID + (col & 63), bf);
  else if (k == EDIM) v = ldf(mb1, col, bf);
  W1t[idx] = f2bf_bits(v);
}

// ---------------- weight prep: tail (MLP+predictor) -> bf16 [N][Kp], K-pad --
__global__ __launch_bounds__(256) void prep_tail(
    const void* __restrict__ mlpW0, const void* __restrict__ mlpW1,
    const void* __restrict__ mlpW2, const void* __restrict__ mlpW3,
    const void* __restrict__ predW0, const void* __restrict__ predW1,
    unsigned short* __restrict__ T, const int* __restrict__ flag) {
  bool bf = *flag != 0;
  int idx = blockIdx.x * 256 + threadIdx.x;
  const void* src; int N, Kp, Ksrc, off;
  if      (idx < 65536)  { src = mlpW0;  N = 256; Kp = 256; Ksrc = 200; off = 0; }
  else if (idx < 131072) { src = mlpW1;  N = 256; Kp = 256; Ksrc = 256; off = 65536; }
  else if (idx < 196608) { src = mlpW2;  N = 256; Kp = 256; Ksrc = 256; off = 131072; }
  else if (idx < 229376) { src = mlpW3;  N = 128; Kp = 256; Ksrc = 256; off = 196608; }
  else if (idx < 360448) { src = predW0; N = 512; Kp = 256; Ksrc = 256; off = 229376; }
  else if (idx < 622592) { src = predW1; N = 512; Kp = 512; Ksrc = 512; off = 360448; }
  else return;
  int rem = idx - off;
  int n = rem / Kp, k = rem % Kp;
  float v = (k < Ksrc) ? ldf(src, (long)k * N + n, bf) : 0.f;
  T[idx] = f2bf_bits(v);
}

// ---------------- CSR build: histogram / 3-phase scan / fill ----------------
__global__ __launch_bounds__(256) void count_kernel(const int* __restrict__ ei,
                                                    int* __restrict__ cnt) {
  int e = blockIdx.x * 256 + threadIdx.x;
  if (e >= EE) return;
  int c = ei[EE + e];
  c = min(max(c, 0), NN - 1);
  atomicAdd(&cnt[c], 1);
}

__global__ __launch_bounds__(256) void scan_phase1(const int* __restrict__ cnt,
                                                   int* __restrict__ bsum) {
  __shared__ int red[256];
  int tid = threadIdx.x;
  int i = blockIdx.x * 256 + tid;
  red[tid] = (i < NN) ? cnt[i] : 0;
  __syncthreads();
  for (int off = 128; off > 0; off >>= 1) {
    if (tid < off) red[tid] += red[tid + off];
    __syncthreads();
  }
  if (tid == 0) bsum[blockIdx.x] = red[0];
}

__global__ __launch_bounds__(256) void scan_phase2(int* __restrict__ bsum,
                                                   int* __restrict__ offs) {
  __shared__ int buf[256];
  int tid = threadIdx.x;
  int v = (tid < SCAN_B) ? bsum[tid] : 0;
  buf[tid] = v;
  __syncthreads();
  for (int off = 1; off < 256; off <<= 1) {
    int t = (tid >= off) ? buf[tid - off] : 0;
    __syncthreads();
    buf[tid] += t;
    __syncthreads();
  }
  if (tid < SCAN_B) bsum[tid] = buf[tid] - v;  // exclusive block offsets
  if (tid == 255) offs[NN] = buf[255];
}

__global__ __launch_bounds__(256) void scan_phase3(const int* __restrict__ cnt,
                                                   const int* __restrict__ bsum,
                                                   int* __restrict__ offs) {
  __shared__ int buf[256];
  int tid = threadIdx.x;
  int i = blockIdx.x * 256 + tid;
  int v = (i < NN) ? cnt[i] : 0;
  buf[tid] = v;
  __syncthreads();
  for (int off = 1; off < 256; off <<= 1) {
    int t = (tid >= off) ? buf[tid - off] : 0;
    __syncthreads();
    buf[tid] += t;
    __syncthreads();
  }
  if (i < NN) offs[i] = bsum[blockIdx.x] + buf[tid] - v;
}

__global__ __launch_bounds__(256) void fill_kernel(const int* __restrict__ ei,
                                                   const int* __restrict__ offs,
                                                   int* __restrict__ cursor,
                                                   int2* __restrict__ csr_se) {
  int e = blockIdx.x * 256 + threadIdx.x;
  if (e >= EE) return;
  int c = ei[EE + e];
  c = min(max(c, 0), NN - 1);
  int pos = offs[c] + atomicAdd(&cursor[c], 1);
  pos = min(max(pos, 0), EE - 1);
  csr_se[pos] = make_int2(ei[e], e);
}

// ---------------- edge-gate MLP via MFMA: ORIGINAL edge order ---------------
__global__ __launch_bounds__(256) void edge_mlp_mfma(
    const void* __restrict__ eattr, const unsigned short* __restrict__ W1t,
    const void* __restrict__ mW2, const void* __restrict__ mb2,
    float* __restrict__ w_all4, const int* __restrict__ flag) {
  bool bf = *flag != 0;
  int tid = threadIdx.x;
  int wave = tid >> 6, lane = tid & 63;
  int l15 = lane & 15, quad = lane >> 4;

  bf16x8 bfrag[16];
#pragma unroll
  for (int t = 0; t < 16; t++)
    bfrag[t] = *reinterpret_cast<const bf16x8*>(&W1t[(t * 16 + l15) * 32 + quad * 8]);

  float w2v[16];
#pragma unroll
  for (int t = 0; t < 16; t++) w2v[t] = ldf(mW2, t * 16 + l15, bf);
  float b2v0 = ldf(mb2, 0, bf), b2v1 = ldf(mb2, 1, bf);
  float b2v2 = ldf(mb2, 2, bf), b2v3 = ldf(mb2, 3, bf);
  float b2 = b2v0;
  b2 = (l15 == 1) ? b2v1 : b2;
  b2 = (l15 == 2) ? b2v2 : b2;
  b2 = (l15 == 3) ? b2v3 : b2;
  bool o1 = (l15 & 1) != 0;
  bool o2 = (l15 & 2) != 0;

  int ebase = blockIdx.x * 512 + wave * 128;
#pragma unroll 1
  for (int f = 0; f < 8; f++) {
    int fbase = ebase + f * 16;
    if (fbase < EE) {  // EE%16==0 -> whole fragment in-bounds
      long erow = fbase + l15;
      bf16x8 a = (bf16x8){0, 0, 0, 0, 0, 0, 0, 0};
      if (quad < 2) {
        if (bf) {
          uint4 v = *reinterpret_cast<const uint4*>((const bf16*)eattr + erow * EDIM + quad * 8);
          a = *reinterpret_cast<bf16x8*>(&v);
        } else {
          const float4* p =
              reinterpret_cast<const float4*>((const float*)eattr + erow * EDIM + quad * 8);
          float4 v0 = p[0], v1 = p[1];
          a[0] = (short)f2bf_bits(v0.x); a[1] = (short)f2bf_bits(v0.y);
          a[2] = (short)f2bf_bits(v0.z); a[3] = (short)f2bf_bits(v0.w);
          a[4] = (short)f2bf_bits(v1.x); a[5] = (short)f2bf_bits(v1.y);
          a[6] = (short)f2bf_bits(v1.z); a[7] = (short)f2bf_bits(v1.w);
        }
      }
      if (quad == 2) a[0] = (short)0x3F80;  // k=16 element = bf16(1.0): adds b1
      float s00 = 0.f, s01 = 0.f, s02 = 0.f, s03 = 0.f;
      float s10 = 0.f, s11 = 0.f, s12 = 0.f, s13 = 0.f;
      float s20 = 0.f, s21 = 0.f, s22 = 0.f, s23 = 0.f;
      float s30 = 0.f, s31 = 0.f, s32 = 0.f, s33 = 0.f;
#define DO_T(T, S0, S1, S2, S3)                                               \
  {                                                                           \
    f32x4 acc = __builtin_amdgcn_mfma_f32_16x16x32_bf16(                      \
        a, bfrag[T], (f32x4){0.f, 0.f, 0.f, 0.f}, 0, 0, 0);                   \
    S0 += fmaxf(acc.x, 0.f) * w2v[T];                                         \
    S1 += fmaxf(acc.y, 0.f) * w2v[T];                                         \
    S2 += fmaxf(acc.z, 0.f) * w2v[T];                                         \
    S3 += fmaxf(acc.w, 0.f) * w2v[T];                                         \
  }
      DO_T(0,  s00, s01, s02, s03) DO_T(1,  s00, s01, s02, s03)
      DO_T(2,  s00, s01, s02, s03) DO_T(3,  s00, s01, s02, s03)
      DO_T(4,  s10, s11, s12, s13) DO_T(5,  s10, s11, s12, s13)
      DO_T(6,  s10, s11, s12, s13) DO_T(7,  s10, s11, s12, s13)
      DO_T(8,  s20, s21, s22, s23) DO_T(9,  s20, s21, s22, s23)
      DO_T(10, s20, s21, s22, s23) DO_T(11, s20, s21, s22, s23)
      DO_T(12, s30, s31, s32, s33) DO_T(13, s30, s31, s32, s33)
      DO_T(14, s30, s31, s32, s33) DO_T(15, s30, s31, s32, s33)
#undef DO_T
#define RS_STEP1(AR, S0R, S1R) \
  float AR = (o1 ? S1R : S0R) + __shfl_xor(o1 ? S0R : S1R, 1);
      RS_STEP1(a0, s00, s10)
      RS_STEP1(a1, s01, s11)
      RS_STEP1(a2, s02, s12)
      RS_STEP1(a3, s03, s13)
      RS_STEP1(bb0, s20, s30)
      RS_STEP1(bb1, s21, s31)
      RS_STEP1(bb2, s22, s32)
      RS_STEP1(bb3, s23, s33)
#undef RS_STEP1
      float c0 = (o2 ? bb0 : a0) + __shfl_xor(o2 ? a0 : bb0, 2);
      float c1 = (o2 ? bb1 : a1) + __shfl_xor(o2 ? a1 : bb1, 2);
      float c2 = (o2 ? bb2 : a2) + __shfl_xor(o2 ? a2 : bb2, 2);
      float c3 = (o2 ? bb3 : a3) + __shfl_xor(o2 ? a3 : bb3, 2);
      c0 += __shfl_xor(c0, 4); c1 += __shfl_xor(c1, 4);
      c2 += __shfl_xor(c2, 4); c3 += __shfl_xor(c3, 4);
      c0 += __shfl_xor(c0, 8); c1 += __shfl_xor(c1, 8);
      c2 += __shfl_xor(c2, 8); c3 += __shfl_xor(c3, 8);
      if (l15 < NL) {
        float g0 = 1.f / (1.f + __expf(-(c0 + b2)));
        float g1 = 1.f / (1.f + __expf(-(c1 + b2)));
        float g2 = 1.f / (1.f + __expf(-(c2 + b2)));
        float g3 = 1.f / (1.f + __expf(-(c3 + b2)));
        w_all4[(size_t)(fbase + quad * 4 + 0) * 4 + l15] = g0;
        w_all4[(size_t)(fbase + quad * 4 + 1) * 4 + l15] = g1;
        w_all4[(size_t)(fbase + quad * 4 + 2) * 4 + l15] = g2;
        w_all4[(size_t)(fbase + quad * 4 + 3) * 4 + l15] = g3;
      }
    }
  }
}

// ---------------- gather gates into CSR order -------------------------------
__global__ __launch_bounds__(256) void csr_gather(const int2* __restrict__ csr_se,
                                                  const float* __restrict__ w_all4,
                                                  float* __restrict__ csr_val) {
  int k = blockIdx.x * 256 + threadIdx.x;
  if (k >= EE) return;
  int eid = csr_se[k].y;
  eid = min(max(eid, 0), EE - 1);
  float4 w = reinterpret_cast<const float4*>(w_all4)[eid];
  csr_val[k] = w.x;
  csr_val[(size_t)EE + k] = w.y;
  csr_val[2 * (size_t)EE + k] = w.z;
  csr_val[3 * (size_t)EE + k] = w.w;
}

// ---------------- degree / dinv per layer (interleaved float4 out) ----------
__global__ __launch_bounds__(256) void deg_kernel(const int* __restrict__ offs,
                                                  const float* __restrict__ csr_val,
                                                  float* __restrict__ dinv4) {
  int n = blockIdx.x * 256 + threadIdx.x;
  if (n >= NN) return;
  int s = offs[n], e = offs[n + 1];
  float d0 = 1.f, d1 = 1.f, d2 = 1.f, d3 = 1.f;  // self-loop weight 1.0
  for (int k = s; k < e; k++) {
    d0 += csr_val[k];
    d1 += csr_val[EE + k];
    d2 += csr_val[2 * (size_t)EE + k];
    d3 += csr_val[3 * (size_t)EE + k];
  }
  float4 o;
  o.x = rsqrtf(d0); o.y = rsqrtf(d1); o.z = rsqrtf(d2); o.w = rsqrtf(d3);
  reinterpret_cast<float4*>(dinv4)[n] = o;
}

// csr_val[l][k] *= dinv_l[src_k]
__global__ __launch_bounds__(256) void csr_scale_kernel(const int2* __restrict__ csr_se,
                                                        const float* __restrict__ dinv4,
                                                        float* __restrict__ csr_val) {
  int k = blockIdx.x * 256 + threadIdx.x;
  if (k >= EE) return;
  int s = csr_se[k].x;
  s = min(max(s, 0), NN - 1);
  float4 d = reinterpret_cast<const float4*>(dinv4)[s];
  csr_val[k] *= d.x;
  csr_val[(size_t)EE + k] *= d.y;
  csr_val[2 * (size_t)EE + k] *= d.z;
  csr_val[3 * (size_t)EE + k] *= d.w;
}

// ---------------- node GEMM via MFMA: bf16 in/out, f32 bias -----------------
__global__ __launch_bounds__(256) void gemm_nodes_bf16(
    const unsigned short* __restrict__ A16, const unsigned short* __restrict__ Wt,
    const float* __restrict__ bias, unsigned short* __restrict__ out16,
    int relu) {
  __shared__ alignas(16) unsigned short sA[64 * 136];
  __shared__ alignas(16) unsigned short sW[128 * 136];
  int tid = threadIdx.x;
  int rbase = blockIdx.x * 64;

#pragma unroll
  for (int p = 0; p < 8; p++) {
    int idx8 = p * 256 + tid;
    int n = idx8 >> 4, kc = idx8 & 15;
    uint4 v = reinterpret_cast<const uint4*>(Wt)[idx8];
    *reinterpret_cast<uint4*>(&sW[n * 136 + kc * 8]) = v;
  }
#pragma unroll
  for (int p = 0; p < 4; p++) {
    int idx8 = p * 256 + tid;
    int m = idx8 >> 4, kc = idx8 & 15;
    int row = rbase + m;
    uint4 v = make_uint4(0u, 0u, 0u, 0u);
    if (row < NN)
      v = *reinterpret_cast<const uint4*>(&A16[(size_t)row * HID + kc * 8]);
    *reinterpret_cast<uint4*>(&sA[m * 136 + kc * 8]) = v;
  }
  __syncthreads();

  int wave = tid >> 6, lane = tid & 63;
  int l15 = lane & 15, quad = lane >> 4;
  int mstrip = wave * 16;

  f32x4 acc[8];
#pragma unroll
  for (int t = 0; t < 8; t++) acc[t] = (f32x4){0.f, 0.f, 0.f, 0.f};

#pragma unroll
  for (int ks = 0; ks < 4; ks++) {
    int k0 = ks * 32 + quad * 8;
    bf16x8 a = *reinterpret_cast<const bf16x8*>(&sA[(mstrip + l15) * 136 + k0]);
#pragma unroll
    for (int t = 0; t < 8; t++) {
      bf16x8 b = *reinterpret_cast<const bf16x8*>(&sW[(t * 16 + l15) * 136 + k0]);
      acc[t] = __builtin_amdgcn_mfma_f32_16x16x32_bf16(a, b, acc[t], 0, 0, 0);
    }
  }

#pragma unroll
  for (int t = 0; t < 8; t++) {
    int n = t * 16 + l15;
    float bv = bias ? bias[n] : 0.f;
#pragma unroll
    for (int r = 0; r < 4; r++) {
      int row = rbase + mstrip + quad * 4 + r;
      if (row < NN) {
        float o = acc[t][r] + bv;
        if (relu) o = fmaxf(o, 0.f);
        out16[(size_t)row * HID + n] = f2bf_bits(o);
      }
    }
  }
}

// ---------------- tail GEMM via MFMA ----------------------------------------
__global__ __launch_bounds__(256) void gemm_tail_mfma(
    const float* __restrict__ A, int lda, const unsigned short* __restrict__ Wt,
    int Kp, const void* __restrict__ bias, float* __restrict__ outp, int ldo,
    int relu, const int* __restrict__ flag) {
  __shared__ alignas(16) unsigned short sA[64 * 264];
  __shared__ alignas(16) unsigned short sW[64 * 264];
  int tid = threadIdx.x;
  int rbase = blockIdx.x * 64;
  int nbase = blockIdx.y * 64;
  int wave = tid >> 6, lane = tid & 63;
  int l15 = lane & 15, quad = lane >> 4;
  int mstrip = wave * 16;

  f32x4 acc[4];
#pragma unroll
  for (int t = 0; t < 4; t++) acc[t] = (f32x4){0.f, 0.f, 0.f, 0.f};

  for (int kc = 0; kc < Kp; kc += 256) {
#pragma unroll 4
    for (int p = 0; p < 16; p++) {
      int idx = p * 1024 + tid * 4;
      int m = idx >> 8, k = idx & 255;
      float4 v = *reinterpret_cast<const float4*>(&A[(size_t)(rbase + m) * lda + kc + k]);
      ushort4 b;
      b.x = f2bf_bits(v.x); b.y = f2bf_bits(v.y);
      b.z = f2bf_bits(v.z); b.w = f2bf_bits(v.w);
      *reinterpret_cast<ushort4*>(&sA[m * 264 + k]) = b;
    }
#pragma unroll 4
    for (int p = 0; p < 8; p++) {
      int idx8 = p * 256 + tid;
      int n = idx8 >> 5, kk = (idx8 & 31) * 8;
      uint4 v = *reinterpret_cast<const uint4*>(&Wt[(size_t)(nbase + n) * Kp + kc + kk]);
      *reinterpret_cast<uint4*>(&sW[n * 264 + kk]) = v;
    }
    __syncthreads();
#pragma unroll
    for (int ks = 0; ks < 8; ks++) {
      int k0 = ks * 32 + quad * 8;
      bf16x8 a = *reinterpret_cast<const bf16x8*>(&sA[(mstrip + l15) * 264 + k0]);
#pragma unroll
      for (int nt = 0; nt < 4; nt++) {
        bf16x8 b = *reinterpret_cast<const bf16x8*>(&sW[(nt * 16 + l15) * 264 + k0]);
        acc[nt] = __builtin_amdgcn_mfma_f32_16x16x32_bf16(a, b, acc[nt], 0, 0, 0);
      }
    }
    __syncthreads();
  }

  bool bf = *flag != 0;
#pragma unroll
  for (int nt = 0; nt < 4; nt++) {
    int col = nbase + nt * 16 + l15;
    float bv = ldf(bias, col, bf);
#pragma unroll
    for (int r = 0; r < 4; r++) {
      int row = rbase + mstrip + quad * 4 + r;
      float o = acc[nt][r] + bv;
      if (relu) o = fmaxf(o, 0.f);
      outp[(size_t)row * ldo + col] = o;
    }
  }
}

// ---------------- aggregation: 1 wave/node, 16B lane gathers, 4 j-slots -----
// lane = (grp = lane>>4 in 0..3, c16 = lane&15). Per j, grp's 16 lanes load
// the full 256B row (16B each). Group partials combined via shfl_xor 16/32.
// out16[n] = dn*(sum_k val_k*h16[src_k]) + dn^2*h16[n]
__global__ __launch_bounds__(64) void aggregate_kernel(
    const unsigned short* __restrict__ h16, const int* __restrict__ offs,
    const int2* __restrict__ csr_se, const float* __restrict__ csr_val,
    const float* __restrict__ dinv4, int layer,
    unsigned short* __restrict__ out16) {
  int n = blockIdx.x;
  int lane = threadIdx.x;      // 0..63
  int grp = lane >> 4;         // j-slot
  int c16 = lane & 15;         // 16B channel chunk (8 bf16)
  __shared__ int s_src[64];
  __shared__ float s_val[64];
  int start = offs[n], end = offs[n + 1];
  float a0 = 0.f, a1 = 0.f, a2 = 0.f, a3 = 0.f;
  float a4 = 0.f, a5 = 0.f, a6 = 0.f, a7 = 0.f;
  for (int base = start; base < end; base += 64) {
    int k = base + lane;
    if (k < end) {
      s_src[lane] = min(max(csr_se[k].x, 0), NN - 1);
      s_val[lane] = csr_val[k];
    }
    __syncthreads();
    int m = min(64, end - base);
    for (int j = grp; j < m; j += 4) {
      float v = s_val[j];
      uint4 u = *reinterpret_cast<const uint4*>(&h16[(size_t)s_src[j] * HID + c16 * 8]);
      a0 = fmaf(v, bfl(u.x), a0); a1 = fmaf(v, bfh(u.x), a1);
      a2 = fmaf(v, bfl(u.y), a2); a3 = fmaf(v, bfh(u.y), a3);
      a4 = fmaf(v, bfl(u.z), a4); a5 = fmaf(v, bfh(u.z), a5);
      a6 = fmaf(v, bfl(u.w), a6); a7 = fmaf(v, bfh(u.w), a7);
    }
    __syncthreads();
  }
  // combine the 4 j-slot groups (no barriers — in-wave shuffles)
  a0 += __shfl_xor(a0, 16); a1 += __shfl_xor(a1, 16);
  a2 += __shfl_xor(a2, 16); a3 += __shfl_xor(a3, 16);
  a4 += __shfl_xor(a4, 16); a5 += __shfl_xor(a5, 16);
  a6 += __shfl_xor(a6, 16); a7 += __shfl_xor(a7, 16);
  a0 += __shfl_xor(a0, 32); a1 += __shfl_xor(a1, 32);
  a2 += __shfl_xor(a2, 32); a3 += __shfl_xor(a3, 32);
  a4 += __shfl_xor(a4, 32); a5 += __shfl_xor(a5, 32);
  a6 += __shfl_xor(a6, 32); a7 += __shfl_xor(a7, 32);
  if (grp == 0) {
    float dn = dinv4[(size_t)n * 4 + layer];
    float dn2 = dn * dn;
    uint4 su = *reinterpret_cast<const uint4*>(&h16[(size_t)n * HID + c16 * 8]);
    ushort4 o0, o1v;
    o0.x  = f2bf_bits(dn * a0 + dn2 * bfl(su.x));
    o0.y  = f2bf_bits(dn * a1 + dn2 * bfh(su.x));
    o0.z  = f2bf_bits(dn * a2 + dn2 * bfl(su.y));
    o0.w  = f2bf_bits(dn * a3 + dn2 * bfh(su.y));
    o1v.x = f2bf_bits(dn * a4 + dn2 * bfl(su.z));
    o1v.y = f2bf_bits(dn * a5 + dn2 * bfh(su.z));
    o1v.z = f2bf_bits(dn * a6 + dn2 * bfl(su.w));
    o1v.w = f2bf_bits(dn * a7 + dn2 * bfh(su.w));
    *reinterpret_cast<ushort4*>(&out16[(size_t)n * HID + c16 * 8]) = o0;
    *reinterpret_cast<ushort4*>(&out16[(size_t)n * HID + c16 * 8 + 4]) = o1v;
  }
}

// ---------------- mean pool, 2-phase (bf16 input) ---------------------------
__global__ __launch_bounds__(128) void pool_partial(const unsigned short* __restrict__ h16,
                                                    const int* __restrict__ batch,
                                                    float* __restrict__ part) {
  int g = blockIdx.x, chunk = blockIdx.y, c = threadIdx.x;
  int lo = 0, hi = NN;
  while (lo < hi) { int mid = (lo + hi) >> 1; if (batch[mid] < g) lo = mid + 1; else hi = mid; }
  int start = lo;
  hi = NN;
  while (lo < hi) { int mid = (lo + hi) >> 1; if (batch[mid] < g + 1) lo = mid + 1; else hi = mid; }
  int end = lo;
  int len = end - start;
  int per = (len + PCH - 1) / PCH;
  int s = start + chunk * per;
  int e = min(s + per, end);
  float sum = 0.f;
  for (int n = s; n < e; n++) sum += bfl((unsigned)h16[(size_t)n * HID + c]);
  part[((size_t)g * PCH + chunk) * HID + c] = sum;
}

__global__ __launch_bounds__(128) void pool_combine(const float* __restrict__ part,
                                                    const int* __restrict__ batch,
                                                    float* __restrict__ cat) {
  int g = blockIdx.x, c = threadIdx.x;
  int lo = 0, hi = NN;
  while (lo < hi) { int mid = (lo + hi) >> 1; if (batch[mid] < g) lo = mid + 1; else hi = mid; }
  int start = lo;
  hi = NN;
  while (lo < hi) { int mid = (lo + hi) >> 1; if (batch[mid] < g + 1) lo = mid + 1; else hi = mid; }
  int end = lo;
  float s = 0.f;
#pragma unroll
  for (int k = 0; k < PCH; k++) s += part[((size_t)g * PCH + k) * HID + c];
  float cntf = (float)(end - start);
  cat[(size_t)g * PIN + c] = s / fmaxf(cntf, 1.f);
}

// ---------------- final [G,512] @ [512,1] + b -> out ------------------------
__global__ __launch_bounds__(64) void final_kernel(const float* __restrict__ A,
                                                   const void* __restrict__ W,
                                                   const void* __restrict__ b,
                                                   void* __restrict__ outp,
                                                   const int* __restrict__ flag) {
  bool bf = *flag != 0;
  int g = blockIdx.x, lane = threadIdx.x;
  float s = 0.f;
  for (int k = lane; k < PH; k += 64) s = fmaf(A[(size_t)g * PH + k], ldf(W, k, bf), s);
#pragma unroll
  for (int off = 32; off > 0; off >>= 1) s += __shfl_down(s, off);
  if (lane == 0) {
    float r = s + ldf(b, 0, bf);
    if (bf) ((bf16*)outp)[g] = __float2bfloat16(r);
    else    ((float*)outp)[g] = r;
  }
}

// ---------------------------------------------------------------------------
extern "C" void kernel_launch(void* const* d_in, const int* in_sizes, int n_in,
                              void* d_out, int out_size, void* d_ws, size_t ws_size,
                              hipStream_t stream) {
  const void* x      = d_in[0];
  const int*  ei     = (const int*)d_in[1];
  const void* eattr  = d_in[2];
  const int*  batch  = (const int*)d_in[3];
  const void* molf   = d_in[4];
  const void* lin_W  = d_in[5];
  const void* mW1    = d_in[6];
  const void* mb1    = d_in[7];
  const void* mW2    = d_in[8];
  const void* mb2    = d_in[9];
  const void* cbias  = d_in[10];
  const void* gW     = d_in[11];
  const void* gb     = d_in[12];
  const void* mlpW0  = d_in[13];
  const void* mlpb0  = d_in[14];
  const void* mlpW1  = d_in[15];
  const void* mlpb1  = d_in[16];
  const void* mlpW2  = d_in[17];
  const void* mlpb2  = d_in[18];
  const void* mlpW3  = d_in[19];
  const void* mlpb3  = d_in[20];
  const void* predW0 = d_in[21];
  const void* predb0 = d_in[22];
  const void* predW1 = d_in[23];
  const void* predb1 = d_in[24];
  const void* outW   = d_in[25];
  const void* outb   = d_in[26];

  char* base = (char*)d_ws;
  size_t off = 0;
  auto alloc = [&](size_t bytes) -> char* {
    char* p = base + off;
    off = (off + bytes + 255) & ~(size_t)255;
    return p;
  };
  unsigned short* h16  = (unsigned short*)alloc((size_t)NN * HID * 2);
  unsigned short* t16  = (unsigned short*)alloc((size_t)NN * HID * 2);
  float* dinv4    = (float*)alloc((size_t)NN * 4 * 4);
  int*   cnt      = (int*)alloc((size_t)NN * 4);
  int*   offs     = (int*)alloc((size_t)(NN + 1) * 4);
  int*   cursor   = (int*)alloc((size_t)NN * 4);
  int*   bsum     = (int*)alloc((size_t)256 * 4);
  int2*  csr_se   = (int2*)alloc((size_t)EE * 8);
  float* csr_val  = (float*)alloc((size_t)NL * EE * 4);
  float* w_all4   = (float*)alloc((size_t)EE * 4 * 4);
  unsigned short* Wt    = (unsigned short*)alloc((size_t)NL * HID * HID * 2);
  float* bprime   = (float*)alloc((size_t)NL * HID * 4);
  unsigned short* tailW = (unsigned short*)alloc((size_t)622592 * 2);
  unsigned short* edgeW = (unsigned short*)alloc((size_t)256 * 32 * 2);
  int*   flag     = (int*)alloc(256);
  float* part     = (float*)alloc((size_t)GG * PCH * HID * 4);
  float* molf32   = (float*)alloc((size_t)GG * 256 * 4);
  float* m0       = (float*)alloc((size_t)GG * MH * 4);
  float* m1       = (float*)alloc((size_t)GG * MH * 4);
  float* cat      = (float*)alloc((size_t)GG * PIN * 4);
  float* p0       = (float*)alloc((size_t)GG * PH * 4);
  float* p1       = (float*)alloc((size_t)GG * PH * 4);

  hipMemsetAsync(cnt, 0, (size_t)NN * 4, stream);
  hipMemsetAsync(cursor, 0, (size_t)NN * 4, stream);
  hipMemsetAsync(molf32, 0, (size_t)GG * 256 * 4, stream);

  // dtype probe first — everything downstream branches on it
  probe_kernel<<<1, 64, 0, stream>>>((const unsigned short*)x, flag);

  // weight prep (fused layer weights + tail + edge)
  prep_fused_w<<<256, 256, 0, stream>>>(lin_W, gW, Wt, flag);
  prep_fused_b<<<NL, 128, 0, stream>>>(cbias, gW, gb, bprime, flag);
  prep_tail<<<(622592 + 255) / 256, 256, 0, stream>>>(mlpW0, mlpW1, mlpW2, mlpW3,
                                                      predW0, predW1, tailW, flag);
  prep_edge_w<<<32, 256, 0, stream>>>(mW1, mb1, edgeW, flag);

  // x -> bf16 layer state
  {
    int n8 = NN * HID / 8;
    cvt_to_bf16<<<(n8 + 255) / 256, 256, 0, stream>>>(x, h16, n8, flag);
  }
  // edge gates (MFMA, ORIGINAL order, 8 frags/wave, b1 folded)
  edge_mlp_mfma<<<(EE + 511) / 512, 256, 0, stream>>>(eattr, edgeW, mW2, mb2,
                                                      w_all4, flag);
  // CSR build (3-phase parallel scan)
  count_kernel<<<(EE + 255) / 256, 256, 0, stream>>>(ei, cnt);
  scan_phase1<<<SCAN_B, 256, 0, stream>>>(cnt, bsum);
  scan_phase2<<<1, 256, 0, stream>>>(bsum, offs);
  scan_phase3<<<SCAN_B, 256, 0, stream>>>(cnt, bsum, offs);
  fill_kernel<<<(EE + 255) / 256, 256, 0, stream>>>(ei, offs, cursor, csr_se);
  // permute gates to CSR order, degrees, scaling
  csr_gather<<<(EE + 255) / 256, 256, 0, stream>>>(csr_se, w_all4, csr_val);
  deg_kernel<<<(NN + 255) / 256, 256, 0, stream>>>(offs, csr_val, dinv4);
  csr_scale_kernel<<<(EE + 255) / 256, 256, 0, stream>>>(csr_se, dinv4, csr_val);

  // GCN layers (fused): aggregate(h16)->t16; gemm(t16, W'_l, b'_l, relu)->h16
  const int gemm_blocks = (NN + 63) / 64;  // 782
  for (int l = 0; l < NL; l++) {
    aggregate_kernel<<<NN, 64, 0, stream>>>(h16, offs, csr_se,
                                            csr_val + (size_t)l * EE, dinv4, l, t16);
    gemm_nodes_bf16<<<gemm_blocks, 256, 0, stream>>>(
        t16, Wt + (size_t)l * HID * HID, bprime + (size_t)l * HID, h16, 1);
  }

  // pooling -> cat[:, 0:128]  (2-phase, bf16 input)
  pool_partial<<<dim3(GG, PCH), 128, 0, stream>>>(h16, batch, part);
  pool_combine<<<GG, 128, 0, stream>>>(part, batch, cat);

  // molecular MLP -> cat[:, 128:256]  (MFMA tail, K-padded weights)
  cvt_molf<<<(GG * 50 + 255) / 256, 256, 0, stream>>>(molf, molf32, flag);
  gemm_tail_mfma<<<dim3(4, 4), 256, 0, stream>>>(molf32, 256, tailW + 0,      256, mlpb0, m0, 256, 1, flag);
  gemm_tail_mfma<<<dim3(4, 4), 256, 0, stream>>>(m0,     256, tailW + 65536,  256, mlpb1, m1, 256, 1, flag);
  gemm_tail_mfma<<<dim3(4, 4), 256, 0, stream>>>(m1,     256, tailW + 131072, 256, mlpb2, m0, 256, 1, flag);
  gemm_tail_mfma<<<dim3(4, 2), 256, 0, stream>>>(m0,     256, tailW + 196608, 256, mlpb3, cat + MOUT, 256, 1, flag);

  // predictor
  gemm_tail_mfma<<<dim3(4, 8), 256, 0, stream>>>(cat, 256, tailW + 229376, 256, predb0, p0, 512, 1, flag);
  gemm_tail_mfma<<<dim3(4, 8), 256, 0, stream>>>(p0,  512, tailW + 360448, 512, predb1, p1, 512, 1, flag);
  final_kernel<<<GG, 64, 0, stream>>>(p1, outW, outb, d_out, flag);
}